// Round 1
// 902.907 us; speedup vs baseline: 1.3693x; 1.3693x over previous
//
#include <hip/hip_runtime.h>
#include <math.h>

// Problem constants
#define BN 4
#define CC 256
#define HH_ 128
#define WW_ 128
#define HWP (HH_*WW_)           // 16384 pixels
#define TOK (64*HWP)            // 1,048,576 elems per (scale,batch) token matrix

// Workspace (bytes), total ~169.2 MB:
//  qt : bf16 [4 scale][4 b][tok][d]  33,554,432   (token-major, all scales)
//  kt : bf16 same                    33,554,432
//  vt : bf16 scales0-2 [d][tok], scale3 [tok][d]  33,554,432
//  aot: bf16 NHWC [b][y][x][c]       33,554,432   (attention out, conv input)
//  Sbf: bf16 score buffer (reused)   33,554,432
//  wpack: bf16 [256][9][256]          1,179,648
//  stats: 512 fp32                        2,048
//  S3 : fp32 [4][64][64]                 65,536
//  rs0: fp32 [4][4096] rowsums scale0    65,536
//  rs1: fp32 [4][1024]                   16,384
//  rs2: fp32 [4][256]                     4,096
// Aliases: xt = Sbf (dead after proj), yt = aot (dead after proj).
// d_out scratch during attention: Sout (33.5MB, second S buffer for batch
// pairing) + part (33.5MB, fp32 K-split partials). Fully overwritten by conv.

typedef __attribute__((ext_vector_type(8))) short bf16x8;
typedef __attribute__((ext_vector_type(4))) float f32x4;

__device__ __forceinline__ float bf2f(unsigned short u) {
    return __uint_as_float(((unsigned)u) << 16);
}
__device__ __forceinline__ unsigned short f2bf(float f) {
    unsigned u = __float_as_uint(f);
    u += 0x7FFF + ((u >> 16) & 1);
    return (unsigned short)(u >> 16);
}
__device__ __forceinline__ void load4f(const unsigned short* p, float o[4]) {
    ushort4 v = *(const ushort4*)p;
    o[0] = bf2f(v.x); o[1] = bf2f(v.y); o[2] = bf2f(v.z); o[3] = bf2f(v.w);
}
__device__ __forceinline__ float ld1(const unsigned short* p) { return bf2f(*p); }
__device__ __forceinline__ float ld1(const float* p) { return *p; }
__device__ __forceinline__ void st1(unsigned short* p, float v) { *p = f2bf(v); }
__device__ __forceinline__ void st1(float* p, float v) { *p = v; }

// ===========================================================================
// Shared MFMA tile machinery: block = 256 thr = 4 waves; tile M=128,N=128,BK=64
// LDS: As/Bs [128][72] bf16 (pad 8). Wave w covers 64x64 quadrant (wm,wn).
// ===========================================================================
#define LDS_STRIDE 72

struct Tile32 { uint4 v[4]; };   // 32 bf16 per thread per operand per BK-iter

__device__ __forceinline__ Tile32 load_tile_bf16(
    const unsigned short* src, size_t stride, int t)
{
    int r = t >> 1, kc = (t & 1) * 32;
    const uint4* sp = (const uint4*)(src + (size_t)r * stride + kc);
    Tile32 o;
    o.v[0] = sp[0]; o.v[1] = sp[1]; o.v[2] = sp[2]; o.v[3] = sp[3];
    return o;
}

__device__ __forceinline__ Tile32 load_tile_f32(
    const float* src, size_t stride, int t)
{
    int r = t >> 1, kc = (t & 1) * 32;
    const float4* sp = (const float4*)(src + (size_t)r * stride + kc);
    unsigned short tmp[32];
    #pragma unroll
    for (int i = 0; i < 8; i++) {
        float4 v = sp[i];
        tmp[i*4+0] = f2bf(v.x); tmp[i*4+1] = f2bf(v.y);
        tmp[i*4+2] = f2bf(v.z); tmp[i*4+3] = f2bf(v.w);
    }
    Tile32 o;
    const uint4* tp = (const uint4*)tmp;
    o.v[0] = tp[0]; o.v[1] = tp[1]; o.v[2] = tp[2]; o.v[3] = tp[3];
    return o;
}

__device__ __forceinline__ void store_tile(
    unsigned short* lds, const Tile32& d, int t)
{
    int r = t >> 1, kc = (t & 1) * 32;
    uint4* dp = (uint4*)&lds[r * LDS_STRIDE + kc];
    dp[0] = d.v[0]; dp[1] = d.v[1]; dp[2] = d.v[2]; dp[3] = d.v[3];
}

__device__ __forceinline__ void mfma_iter(
    const unsigned short* As, const unsigned short* Bs,
    int wm, int wn, int lr, int quad, f32x4 acc[4][4])
{
    #pragma unroll
    for (int s = 0; s < 2; s++) {
        bf16x8 af[4], bfr[4];
        #pragma unroll
        for (int i = 0; i < 4; i++)
            af[i] = *(const bf16x8*)&As[(wm*64 + i*16 + lr) * LDS_STRIDE + s*32 + quad*8];
        #pragma unroll
        for (int j = 0; j < 4; j++)
            bfr[j] = *(const bf16x8*)&Bs[(wn*64 + j*16 + lr) * LDS_STRIDE + s*32 + quad*8];
        #pragma unroll
        for (int i = 0; i < 4; i++)
            #pragma unroll
            for (int j = 0; j < 4; j++)
                acc[i][j] = __builtin_amdgcn_mfma_f32_16x16x32_bf16(
                    af[i], bfr[j], acc[i][j], 0, 0, 0);
    }
}

// ---------------------------------------------------------------------------
__global__ __launch_bounds__(256) void zero_kernel(float* __restrict__ p)
{
    p[blockIdx.x * 256 + threadIdx.x] = 0.f;
}

// ---------------------------------------------------------------------------
// NCHW fp32 -> NHWC bf16 for x and y. grid (256 p-tiles, 4 c-tiles, 8)
__global__ __launch_bounds__(256) void nchw_to_nhwc(
    const float* __restrict__ x, const float* __restrict__ y,
    unsigned short* __restrict__ xt, unsigned short* __restrict__ yt)
{
    __shared__ unsigned short T[64 * 72];
    int z = blockIdx.z;
    int b = z & 3, which = z >> 2;
    const float* src = (which ? y : x) + (size_t)b * CC * HWP;
    unsigned short* dst = (which ? yt : xt) + (size_t)b * HWP * CC;
    int p0 = blockIdx.x * 64, c0 = blockIdx.y * 64;
    int t = threadIdx.x;

    int cl = t >> 2, pc = (t & 3) * 16;
    #pragma unroll
    for (int e = 0; e < 16; e += 4) {
        float4 v = *(const float4*)&src[(size_t)(c0 + cl) * HWP + p0 + pc + e];
        T[(pc + e + 0) * 72 + cl] = f2bf(v.x);
        T[(pc + e + 1) * 72 + cl] = f2bf(v.y);
        T[(pc + e + 2) * 72 + cl] = f2bf(v.z);
        T[(pc + e + 3) * 72 + cl] = f2bf(v.w);
    }
    __syncthreads();
    int p = t >> 2, cc = (t & 3) * 16;
    uint4 a = *(uint4*)&T[p * 72 + cc];
    uint4 bsec = *(uint4*)&T[p * 72 + cc + 8];
    uint4* dp = (uint4*)&dst[(size_t)(p0 + p) * CC + c0 + cc];
    dp[0] = a; dp[1] = bsec;
}

// ---------------------------------------------------------------------------
// pack conv weights: Wo [o][c][3][3] fp32 -> wpack [o][tap][c] bf16
__global__ __launch_bounds__(256) void wpack_kernel(
    const float* __restrict__ Wo, unsigned short* __restrict__ wpack)
{
    int o = blockIdx.x, c = threadIdx.x;
    const float* wr = Wo + ((size_t)o * CC + c) * 9;
    #pragma unroll
    for (int tap = 0; tap < 9; tap++)
        wpack[((size_t)o * 9 + tap) * CC + c] = f2bf(wr[tap]);
}

// ---------------------------------------------------------------------------
// proj: C[o][p] = W[o][c] * X[p][c]^T + bias, scattered to token layouts.
// grid: (128 p-tiles, 2 o-tiles, 12) z = which*4 + b
__global__ __launch_bounds__(256) void proj_gemm(
    const unsigned short* __restrict__ xt, const unsigned short* __restrict__ yt,
    const float* __restrict__ Wq, const float* __restrict__ bq,
    const float* __restrict__ Wk, const float* __restrict__ bk,
    const float* __restrict__ Wv, const float* __restrict__ bv,
    unsigned short* __restrict__ qt, unsigned short* __restrict__ kt,
    unsigned short* __restrict__ vt)
{
    __shared__ unsigned short As[128 * LDS_STRIDE], Bs[128 * LDS_STRIDE];
    int z = blockIdx.z, b = z & 3, which = z >> 2;
    const unsigned short* src = (which == 0) ? xt : yt;
    const float* Wm   = (which == 0) ? Wq : (which == 1 ? Wk : Wv);
    const float* bias = (which == 0) ? bq : (which == 1 ? bk : bv);
    unsigned short* outp = (which == 0) ? qt : (which == 1 ? kt : vt);

    int m0 = blockIdx.y * 128;   // output channels
    int n0 = blockIdx.x * 128;   // pixels
    const float* A = Wm + (size_t)m0 * CC;
    const unsigned short* B = src + ((size_t)b * HWP + n0) * CC;

    int t = threadIdx.x, w = t >> 6, lane = t & 63;
    int quad = lane >> 4, lr = lane & 15, wm = w >> 1, wn = w & 1;

    f32x4 acc[4][4];
    #pragma unroll
    for (int i = 0; i < 4; i++)
        #pragma unroll
        for (int j = 0; j < 4; j++) acc[i][j] = (f32x4){0.f, 0.f, 0.f, 0.f};

    for (int k0 = 0; k0 < CC; k0 += 64) {
        Tile32 ta = load_tile_f32(A + k0, CC, t);
        Tile32 tb = load_tile_bf16(B + k0, CC, t);
        __syncthreads();
        store_tile(As, ta, t); store_tile(Bs, tb, t);
        __syncthreads();
        mfma_iter(As, Bs, wm, wn, lr, quad, acc);
    }

    #pragma unroll
    for (int i = 0; i < 4; i++) {
        int obase = m0 + wm * 64 + i * 16 + quad * 4;
        #pragma unroll
        for (int rr = 0; rr < 4; rr++) {
            int o = obase + rr;
            int s = o >> 6, lg = s + 1;
            int ch = o & 63;
            float bia = bias[o];
            unsigned short* ob = outp + ((size_t)s * 4 + b) * TOK;
            #pragma unroll
            for (int j = 0; j < 4; j++) {
                int p = n0 + wn * 64 + j * 16 + lr;
                int yy = p >> 7, xx = p & 127;
                int oy = yy >> lg, wy = yy & ((1 << lg) - 1);
                int ox = xx >> lg, wx = xx & ((1 << lg) - 1);
                int tokn = (oy << (7 - lg)) + ox;
                int didx = (ch << (2 * lg)) + (wy << lg) + wx;
                size_t idx;
                if (which == 2 && s < 3)
                    idx = ((size_t)didx << (14 - 2 * lg)) + tokn;   // [d][tok]
                else
                    idx = ((size_t)tokn << (6 + 2 * lg)) + didx;    // [tok][d]
                ob[idx] = f2bf(acc[i][j][rr] + bia);
            }
        }
    }
}

// ---------------------------------------------------------------------------
// E = exp(sc * Q K^T), plus per-row sums via shfl-reduce + atomicAdd.
// Q,K bf16 [tok][d]. grid: (NTOK/128, NTOK/128, nb)
// S1 != nullptr: bz selects S0/S1 (batch pairing, nb==2).
// S1 == nullptr: S contiguous per bz.
template<int NTOK, int DD>
__global__ __launch_bounds__(256) void s_gemm_exp(
    const unsigned short* __restrict__ Qb, const unsigned short* __restrict__ Kb,
    unsigned short* __restrict__ S0, unsigned short* __restrict__ S1,
    float* __restrict__ rsg, float sc)
{
    __shared__ unsigned short As[128 * LDS_STRIDE], Bs[128 * LDS_STRIDE];
    int bz = blockIdx.z;
    int m0 = blockIdx.y * 128, n0 = blockIdx.x * 128;
    const unsigned short* Q = Qb + (size_t)bz * TOK + (size_t)m0 * DD;
    const unsigned short* K = Kb + (size_t)bz * TOK + (size_t)n0 * DD;
    unsigned short* S;
    if (S1) S = bz ? S1 : S0;
    else    S = S0 + (size_t)bz * NTOK * NTOK;
    float* rs = rsg + (size_t)bz * NTOK;

    int t = threadIdx.x, w = t >> 6, lane = t & 63;
    int quad = lane >> 4, lr = lane & 15, wm = w >> 1, wn = w & 1;

    f32x4 acc[4][4];
    #pragma unroll
    for (int i = 0; i < 4; i++)
        #pragma unroll
        for (int j = 0; j < 4; j++) acc[i][j] = (f32x4){0.f, 0.f, 0.f, 0.f};

    for (int k0 = 0; k0 < DD; k0 += 64) {
        Tile32 ta = load_tile_bf16(Q + k0, DD, t);
        Tile32 tb = load_tile_bf16(K + k0, DD, t);
        __syncthreads();
        store_tile(As, ta, t); store_tile(Bs, tb, t);
        __syncthreads();
        mfma_iter(As, Bs, wm, wn, lr, quad, acc);
    }

    #pragma unroll
    for (int i = 0; i < 4; i++) {
        int m = m0 + wm * 64 + i * 16 + quad * 4;
        float rsum[4] = {0.f, 0.f, 0.f, 0.f};
        #pragma unroll
        for (int j = 0; j < 4; j++) {
            int n = n0 + wn * 64 + j * 16 + lr;
            #pragma unroll
            for (int rr = 0; rr < 4; rr++) {
                float e = __expf(acc[i][j][rr] * sc);
                S[(size_t)(m + rr) * NTOK + n] = f2bf(e);
                rsum[rr] += e;
            }
        }
        #pragma unroll
        for (int rr = 0; rr < 4; rr++) {
            float v = rsum[rr];
            v += __shfl_xor(v, 1);
            v += __shfl_xor(v, 2);
            v += __shfl_xor(v, 4);
            v += __shfl_xor(v, 8);
            if (lr == 0) atomicAdd(&rs[m + rr], v);
        }
    }
}

// ---------------------------------------------------------------------------
// O = E V with V stored [d][tok]; divides by rowsum; NHWC bf16 scatter.
// grid: (DD/128, NTOK/128, nb) — scales 1,2.
template<int NTOK, int DD, int LG, int CH0>
__global__ __launch_bounds__(256) void o_gemm(
    const unsigned short* __restrict__ Pb, const unsigned short* __restrict__ Vb,
    const float* __restrict__ rsg, unsigned short* __restrict__ aot, int b0)
{
    __shared__ unsigned short As[128 * LDS_STRIDE], Bs[128 * LDS_STRIDE];
    int bz = blockIdx.z, b = b0 + bz;
    int m0 = blockIdx.y * 128, n0 = blockIdx.x * 128;
    const unsigned short* P = Pb + (size_t)bz * NTOK * NTOK + (size_t)m0 * NTOK;
    const unsigned short* V = Vb + (size_t)bz * TOK + (size_t)n0 * NTOK;
    const float* rs = rsg + (size_t)bz * NTOK;

    int t = threadIdx.x, w = t >> 6, lane = t & 63;
    int quad = lane >> 4, lr = lane & 15, wm = w >> 1, wn = w & 1;

    f32x4 acc[4][4];
    #pragma unroll
    for (int i = 0; i < 4; i++)
        #pragma unroll
        for (int j = 0; j < 4; j++) acc[i][j] = (f32x4){0.f, 0.f, 0.f, 0.f};

    for (int k0 = 0; k0 < NTOK; k0 += 64) {
        Tile32 ta = load_tile_bf16(P + k0, NTOK, t);
        Tile32 tb = load_tile_bf16(V + k0, NTOK, t);
        __syncthreads();
        store_tile(As, ta, t); store_tile(Bs, tb, t);
        __syncthreads();
        mfma_iter(As, Bs, wm, wn, lr, quad, acc);
    }

    #pragma unroll
    for (int i = 0; i < 4; i++) {
        int tb0 = m0 + wm * 64 + i * 16 + quad * 4;
        #pragma unroll
        for (int rr = 0; rr < 4; rr++) {
            int tokn = tb0 + rr;
            float inv = 1.f / rs[tokn];
            int oy = tokn >> (7 - LG), ox = tokn & ((1 << (7 - LG)) - 1);
            #pragma unroll
            for (int j = 0; j < 4; j++) {
                int d = n0 + wn * 64 + j * 16 + lr;
                int ch = d >> (2 * LG);
                int r2 = d & ((1 << (2 * LG)) - 1);
                int wy = r2 >> LG, wx = r2 & ((1 << LG) - 1);
                int yy = (oy << LG) + wy, xx = (ox << LG) + wx;
                aot[((size_t)b * HWP + yy * WW_ + xx) * CC + CH0 + ch] =
                    f2bf(acc[i][j][rr] * inv);
            }
        }
    }
}

// ---------------------------------------------------------------------------
// Scale-0 PV, 4-way K-split + batch pair: partial O (fp32 [tok][d]) per
// (batch,split). grid (2 d-tiles, 32 tok-tiles, 8) z = bsel*4 + sp.
__global__ __launch_bounds__(256) void o0_split(
    const unsigned short* __restrict__ P0, const unsigned short* __restrict__ P1,
    const unsigned short* __restrict__ Vb, float* __restrict__ part)
{
    __shared__ unsigned short As[128 * LDS_STRIDE], Bs[128 * LDS_STRIDE];
    int bz = blockIdx.z;
    int bsel = bz >> 2, sp = bz & 3;
    int m0 = blockIdx.y * 128;   // token tile
    int n0 = blockIdx.x * 128;   // d tile
    const unsigned short* P = (bsel ? P1 : P0) + (size_t)m0 * 4096 + sp * 1024;
    const unsigned short* V = Vb + (size_t)bsel * TOK + (size_t)n0 * 4096 + sp * 1024;
    float* op = part + (size_t)bz * TOK;

    int t = threadIdx.x, w = t >> 6, lane = t & 63;
    int quad = lane >> 4, lr = lane & 15, wm = w >> 1, wn = w & 1;

    f32x4 acc[4][4];
    #pragma unroll
    for (int i = 0; i < 4; i++)
        #pragma unroll
        for (int j = 0; j < 4; j++) acc[i][j] = (f32x4){0.f, 0.f, 0.f, 0.f};

    for (int k0 = 0; k0 < 1024; k0 += 64) {
        Tile32 ta = load_tile_bf16(P + k0, 4096, t);
        Tile32 tb = load_tile_bf16(V + k0, 4096, t);
        __syncthreads();
        store_tile(As, ta, t); store_tile(Bs, tb, t);
        __syncthreads();
        mfma_iter(As, Bs, wm, wn, lr, quad, acc);
    }

    #pragma unroll
    for (int i = 0; i < 4; i++) {
        int tb0 = m0 + wm * 64 + i * 16 + quad * 4;
        #pragma unroll
        for (int rr = 0; rr < 4; rr++) {
            int tokn = tb0 + rr;
            #pragma unroll
            for (int j = 0; j < 4; j++) {
                int d = n0 + wn * 64 + j * 16 + lr;
                op[(size_t)tokn * 256 + d] = acc[i][j][rr];
            }
        }
    }
}

// ---------------------------------------------------------------------------
// Sum 4 K-split partials, divide by rowsum, scatter NHWC (ch-contiguous 128B
// runs per wave). grid (256 tok-tiles of 16, 2 batches).
__global__ __launch_bounds__(256) void combine0(
    const float* __restrict__ part, const float* __restrict__ rs,
    unsigned short* __restrict__ aot, int b0)
{
    int bsel = blockIdx.y, b = b0 + bsel;
    int tok0 = blockIdx.x * 16;
    const float* p = part + (size_t)bsel * 4 * TOK;
    int t = threadIdx.x;
    int w = t >> 6, ch = t & 63;
    int wy = w >> 1, wx = w & 1;
    #pragma unroll 4
    for (int u = 0; u < 16; u++) {
        int tok = tok0 + u;
        size_t base = (size_t)tok * 256 + ch * 4 + w;
        float v = p[base] + p[base + TOK] + p[base + 2 * (size_t)TOK]
                + p[base + 3 * (size_t)TOK];
        v *= 1.f / rs[(size_t)bsel * 4096 + tok];
        int oy = tok >> 6, ox = tok & 63;
        int yy = oy * 2 + wy, xx = ox * 2 + wx;
        aot[((size_t)b * HWP + yy * WW_ + xx) * CC + ch] = f2bf(v);
    }
}

// ---------------------------------------------------------------------------
// conv3x3: out[o][p] = sum_{tap,c} wpack[o][tap][c] * aot[p+shift][c] + bo
// grid: (128 y-rows, 2 o-tiles, 4 b)
__device__ __forceinline__ Tile32 load_tile_conv(
    const unsigned short* aob, int ys, int dx, int cbase, int t)
{
    int r = t >> 1, kc = (t & 1) * 32;
    int xs = r + dx;
    Tile32 o;
    if (ys >= 0 && ys < HH_ && xs >= 0 && xs < WW_) {
        const uint4* sp = (const uint4*)(aob + ((size_t)ys * WW_ + xs) * CC + cbase + kc);
        o.v[0] = sp[0]; o.v[1] = sp[1]; o.v[2] = sp[2]; o.v[3] = sp[3];
    } else {
        uint4 zz = make_uint4(0, 0, 0, 0);
        o.v[0] = zz; o.v[1] = zz; o.v[2] = zz; o.v[3] = zz;
    }
    return o;
}

__global__ __launch_bounds__(256) void conv_gemm(
    const unsigned short* __restrict__ aot, const unsigned short* __restrict__ wpack,
    const float* __restrict__ bo, float* __restrict__ zout)
{
    __shared__ unsigned short As[128 * LDS_STRIDE], Bs[128 * LDS_STRIDE];
    int yrow = blockIdx.x;
    int o0 = blockIdx.y * 128;
    int b = blockIdx.z;
    const unsigned short* aob = aot + (size_t)b * HWP * CC;
    const unsigned short* wsrc = wpack + (size_t)o0 * 2304;

    int t = threadIdx.x, w = t >> 6, lane = t & 63;
    int quad = lane >> 4, lr = lane & 15, wm = w >> 1, wn = w & 1;

    f32x4 acc[4][4];
    #pragma unroll
    for (int i = 0; i < 4; i++)
        #pragma unroll
        for (int j = 0; j < 4; j++) acc[i][j] = (f32x4){0.f, 0.f, 0.f, 0.f};

    for (int tap = 0; tap < 9; tap++) {
        int dy = tap / 3 - 1, dx = tap % 3 - 1;
        int ys = yrow + dy;
        for (int cb = 0; cb < CC; cb += 64) {
            Tile32 ta = load_tile_bf16(wsrc + tap * CC + cb, 2304, t);
            Tile32 tb = load_tile_conv(aob, ys, dx, cb, t);
            __syncthreads();
            store_tile(As, ta, t); store_tile(Bs, tb, t);
            __syncthreads();
            mfma_iter(As, Bs, wm, wn, lr, quad, acc);
        }
    }

    #pragma unroll
    for (int i = 0; i < 4; i++) {
        int ob = o0 + wm * 64 + i * 16 + quad * 4;
        #pragma unroll
        for (int j = 0; j < 4; j++) {
            int x = wn * 64 + j * 16 + lr;
            #pragma unroll
            for (int rr = 0; rr < 4; rr++) {
                int o = ob + rr;
                zout[((size_t)(b * CC + o)) * HWP + yrow * WW_ + x] =
                    acc[i][j][rr] + bo[o];
            }
        }
    }
}

// ---------------------------------------------------------------------------
// scale-3 S: N=64, D=16384, K-split 16, fp32 atomic acc. grid (1,1,64)
__global__ __launch_bounds__(256) void s3_kernel(
    const unsigned short* __restrict__ Qb, const unsigned short* __restrict__ Kb,
    float* __restrict__ S, float sc)
{
    const int N = 64, D = 16384, KLEN = 1024;
    int b = blockIdx.z >> 4, kc = blockIdx.z & 15;
    const unsigned short* Q = Qb + (size_t)b * TOK;
    const unsigned short* K = Kb + (size_t)b * TOK;
    float* Sb = S + (size_t)b * N * N;
    int k0 = kc * KLEN;

    __shared__ float As[16][64], Bs[16][64];
    int t = threadIdx.x, tx = t & 15, ty = t >> 4, r = t >> 2, q = t & 3;

    float acc[4][4] = {};
    for (int kk = k0; kk < k0 + KLEN; kk += 16) {
        float a4[4], b4[4];
        load4f(&Q[(size_t)r * D + kk + q * 4], a4);
        load4f(&K[(size_t)r * D + kk + q * 4], b4);
        __syncthreads();
        As[q*4+0][r] = a4[0]; As[q*4+1][r] = a4[1]; As[q*4+2][r] = a4[2]; As[q*4+3][r] = a4[3];
        Bs[q*4+0][r] = b4[0]; Bs[q*4+1][r] = b4[1]; Bs[q*4+2][r] = b4[2]; Bs[q*4+3][r] = b4[3];
        __syncthreads();
        #pragma unroll
        for (int k = 0; k < 16; k++) {
            float4 af = *(const float4*)&As[k][ty*4];
            float4 bf = *(const float4*)&Bs[k][tx*4];
            float ar[4] = {af.x, af.y, af.z, af.w};
            float br[4] = {bf.x, bf.y, bf.z, bf.w};
            #pragma unroll
            for (int ii = 0; ii < 4; ii++)
                #pragma unroll
                for (int jj = 0; jj < 4; jj++)
                    acc[ii][jj] = fmaf(ar[ii], br[jj], acc[ii][jj]);
        }
    }

    #pragma unroll
    for (int ii = 0; ii < 4; ii++)
        #pragma unroll
        for (int jj = 0; jj < 4; jj++)
            atomicAdd(&Sb[(size_t)(ty * 4 + ii) * N + tx * 4 + jj], acc[ii][jj] * sc);
}

// ---------------------------------------------------------------------------
// in-place row softmax (scale 3 only). grid: (n, nb)
template<typename T>
__global__ __launch_bounds__(256) void softmax_kernel(T* __restrict__ S, int n)
{
    int b = blockIdx.y;
    int row = blockIdx.x;
    T* rp = S + (size_t)b * n * n + (size_t)row * n;
    __shared__ float red[256];
    int t = threadIdx.x;

    float m = -1e30f;
    for (int j = t; j < n; j += 256) m = fmaxf(m, ld1(&rp[j]));
    red[t] = m; __syncthreads();
    for (int s = 128; s > 0; s >>= 1) { if (t < s) red[t] = fmaxf(red[t], red[t + s]); __syncthreads(); }
    m = red[0]; __syncthreads();

    float sum = 0.f;
    for (int j = t; j < n; j += 256) { float e = __expf(ld1(&rp[j]) - m); st1(&rp[j], e); sum += e; }
    red[t] = sum; __syncthreads();
    for (int s = 128; s > 0; s >>= 1) { if (t < s) red[t] += red[t + s]; __syncthreads(); }
    float inv = 1.f / red[0];
    for (int j = t; j < n; j += 256) st1(&rp[j], ld1(&rp[j]) * inv);
}

// ---------------------------------------------------------------------------
// scale-3 O = P(fp32 64x64) V(bf16 [tok][d]); NHWC bf16 out. grid (1,256,4)
__global__ __launch_bounds__(256) void o3_kernel(
    const float* __restrict__ P, const unsigned short* __restrict__ Vb,
    unsigned short* __restrict__ aot)
{
    const int N = 64, D = 16384, LG = 4, CH0 = 192;
    int bz = blockIdx.z;
    const float* Pb = P + (size_t)bz * N * N;
    const unsigned short* V = Vb + (size_t)bz * TOK;
    int i0 = blockIdx.x * 64, d0 = blockIdx.y * 64;

    __shared__ float Ps[16][64];
    __shared__ float Vs[16][64];
    int t = threadIdx.x, tx = t & 15, ty = t >> 4, r = t >> 2, q = t & 3;
    int vr = t >> 4, vq = t & 15;

    float acc[4][4] = {};
    for (int j0 = 0; j0 < N; j0 += 16) {
        float p4[4], v4[4];
        float4 pv = *(const float4*)&Pb[(size_t)(i0 + r) * N + j0 + q * 4];
        p4[0] = pv.x; p4[1] = pv.y; p4[2] = pv.z; p4[3] = pv.w;
        load4f(&V[(size_t)(j0 + vr) * D + d0 + vq * 4], v4);
        __syncthreads();
        Ps[q*4+0][r] = p4[0]; Ps[q*4+1][r] = p4[1]; Ps[q*4+2][r] = p4[2]; Ps[q*4+3][r] = p4[3];
        Vs[vr][vq*4+0] = v4[0]; Vs[vr][vq*4+1] = v4[1]; Vs[vr][vq*4+2] = v4[2]; Vs[vr][vq*4+3] = v4[3];
        __syncthreads();
        #pragma unroll
        for (int k = 0; k < 16; k++) {
            float4 pf = *(const float4*)&Ps[k][ty*4];
            float4 vf = *(const float4*)&Vs[k][tx*4];
            float pr[4] = {pf.x, pf.y, pf.z, pf.w};
            float vrr[4] = {vf.x, vf.y, vf.z, vf.w};
            #pragma unroll
            for (int ii = 0; ii < 4; ii++)
                #pragma unroll
                for (int jj = 0; jj < 4; jj++)
                    acc[ii][jj] = fmaf(pr[ii], vrr[jj], acc[ii][jj]);
        }
    }

    #pragma unroll
    for (int ii = 0; ii < 4; ii++) {
        int tokn = i0 + ty * 4 + ii;
        int oy = tokn >> (7 - LG), ox = tokn & ((1 << (7 - LG)) - 1);
        #pragma unroll
        for (int jj = 0; jj < 4; jj++) {
            int d = d0 + tx * 4 + jj;
            int ch = d >> (2 * LG);
            int r2 = d & ((1 << (2 * LG)) - 1);
            int wy = r2 >> LG, wx = r2 & ((1 << LG) - 1);
            int yy = (oy << LG) + wy, xx = (ox << LG) + wx;
            aot[((size_t)bz * HWP + yy * WW_ + xx) * CC + CH0 + ch] = f2bf(acc[ii][jj]);
        }
    }
}

// ---------------------------------------------------------------------------
__global__ __launch_bounds__(256) void bn_stats_kernel(
    const float* __restrict__ z, const float* __restrict__ gamma,
    const float* __restrict__ beta, float* __restrict__ stats)
{
    int c = blockIdx.x;
    int t = threadIdx.x;
    float s = 0.f, s2 = 0.f;
    for (int i = t; i < BN * HWP; i += 256) {
        int b = i >> 14, p = i & (HWP - 1);
        float v = z[(((size_t)b * CC + c) << 14) + p];
        s += v; s2 = fmaf(v, v, s2);
    }
    __shared__ float r1[256], r2[256];
    r1[t] = s; r2[t] = s2; __syncthreads();
    for (int st = 128; st > 0; st >>= 1) {
        if (t < st) { r1[t] += r1[t + st]; r2[t] += r2[t + st]; }
        __syncthreads();
    }
    if (t == 0) {
        float inv_n = 1.f / (BN * HWP);
        float mean = r1[0] * inv_n;
        float var = r2[0] * inv_n - mean * mean;
        float rstd = rsqrtf(var + 1e-5f);
        float gs = gamma[c] * rstd;
        stats[c] = gs;
        stats[CC + c] = beta[c] - mean * gs;
    }
}

__global__ __launch_bounds__(256) void bn_apply_kernel(
    float* __restrict__ z, const float* __restrict__ stats)
{
    size_t i4 = (size_t)blockIdx.x * 256 + threadIdx.x;
    size_t idx = i4 * 4;
    int c = (int)((idx >> 14) & 255);
    float gs = stats[c], gb = stats[CC + c];
    float4 v = *(float4*)&z[idx];
    v.x = fmaf(v.x, gs, gb); v.y = fmaf(v.y, gs, gb);
    v.z = fmaf(v.z, gs, gb); v.w = fmaf(v.w, gs, gb);
    v.x = v.x >= 0.f ? v.x : 0.2f * v.x;
    v.y = v.y >= 0.f ? v.y : 0.2f * v.y;
    v.z = v.z >= 0.f ? v.z : 0.2f * v.z;
    v.w = v.w >= 0.f ? v.w : 0.2f * v.w;
    *(float4*)&z[idx] = v;
}

// ---------------------------------------------------------------------------
extern "C" void kernel_launch(void* const* d_in, const int* in_sizes, int n_in,
                              void* d_out, int out_size, void* d_ws, size_t ws_size,
                              hipStream_t stream)
{
    const float* x     = (const float*)d_in[0];
    const float* y     = (const float*)d_in[1];
    const float* Wq    = (const float*)d_in[2];
    const float* bq    = (const float*)d_in[3];
    const float* Wk    = (const float*)d_in[4];
    const float* bk    = (const float*)d_in[5];
    const float* Wv    = (const float*)d_in[6];
    const float* bv    = (const float*)d_in[7];
    const float* Wo    = (const float*)d_in[8];
    const float* bo    = (const float*)d_in[9];
    const float* gamma = (const float*)d_in[10];
    const float* beta  = (const float*)d_in[11];
    float* out = (float*)d_out;

    unsigned short* qt    = (unsigned short*)d_ws;
    unsigned short* kt    = qt + (size_t)16777216;
    unsigned short* vt    = kt + (size_t)16777216;
    unsigned short* aot   = vt + (size_t)16777216;
    unsigned short* Sbf   = aot + (size_t)16777216;
    unsigned short* wpack = Sbf + (size_t)16777216;
    float* stats = (float*)(wpack + (size_t)589824);
    float* S3    = stats + 512;
    float* rs0   = S3 + 16384;     // [4][4096]
    float* rs1   = rs0 + 16384;    // [4][1024]
    float* rs2   = rs1 + 4096;     // [4][256]
    // aliases (dead after proj_gemm):
    unsigned short* xt = Sbf;
    unsigned short* yt = aot;
    // d_out scratch during attention (dead until conv_gemm):
    unsigned short* Sout = (unsigned short*)d_out;                 // 33.5 MB
    float* part = (float*)((char*)d_out + (size_t)33554432);       // 33.5 MB

    dim3 blk(256);

    // zero S3 + rs0 + rs1 + rs2 (contiguous: 16384+16384+4096+1024 = 37888 f)
    zero_kernel<<<dim3(148), blk, 0, stream>>>(S3);
    nchw_to_nhwc<<<dim3(256, 4, 8), blk, 0, stream>>>(x, y, xt, yt);
    wpack_kernel<<<dim3(256), blk, 0, stream>>>(Wo, wpack);

    proj_gemm<<<dim3(128, 2, 12), blk, 0, stream>>>(
        xt, yt, Wq, bq, Wk, bk, Wv, bv, qt, kt, vt);

    // scale 0: n=4096, D=256, window 2 — batch pairs (Sbf + d_out as S bufs),
    // exp fused into score GEMM, PV 4-way K-split into fp32 partials.
    for (int pr = 0; pr < 2; pr++) {
        int b0 = pr * 2;
        s_gemm_exp<4096, 256><<<dim3(32, 32, 2), blk, 0, stream>>>(
            qt + (size_t)b0 * TOK, kt + (size_t)b0 * TOK,
            Sbf, Sout, rs0 + (size_t)b0 * 4096, 1.f / 16.f);
        o0_split<<<dim3(2, 32, 8), blk, 0, stream>>>(
            Sbf, Sout, vt + (size_t)b0 * TOK, part);
        combine0<<<dim3(256, 2), blk, 0, stream>>>(
            part, rs0 + (size_t)b0 * 4096, aot, b0);
    }
    // scale 1: n=1024, D=1024, window 4
    s_gemm_exp<1024, 1024><<<dim3(8, 8, 4), blk, 0, stream>>>(
        qt + (size_t)4 * TOK, kt + (size_t)4 * TOK, Sbf, nullptr, rs1, 1.f / 32.f);
    o_gemm<1024, 1024, 2, 64><<<dim3(8, 8, 4), blk, 0, stream>>>(
        Sbf, vt + (size_t)4 * TOK, rs1, aot, 0);
    // scale 2: n=256, D=4096, window 8
    s_gemm_exp<256, 4096><<<dim3(2, 2, 4), blk, 0, stream>>>(
        qt + (size_t)8 * TOK, kt + (size_t)8 * TOK, Sbf, nullptr, rs2, 1.f / 64.f);
    o_gemm<256, 4096, 3, 128><<<dim3(32, 2, 4), blk, 0, stream>>>(
        Sbf, vt + (size_t)8 * TOK, rs2, aot, 0);
    // scale 3: n=64, D=16384, window 16 — fp32 K-split path (unchanged)
    s3_kernel<<<dim3(1, 1, 64), blk, 0, stream>>>(
        qt + (size_t)12 * TOK, kt + (size_t)12 * TOK, S3, 1.f / 128.f);
    softmax_kernel<float><<<dim3(64, 4), blk, 0, stream>>>(S3, 64);
    o3_kernel<<<dim3(1, 256, 4), blk, 0, stream>>>(S3, vt + (size_t)12 * TOK, aot);

    conv_gemm<<<dim3(128, 2, 4), blk, 0, stream>>>(aot, wpack, bo, out);
    bn_stats_kernel<<<dim3(CC), blk, 0, stream>>>(out, gamma, beta, stats);
    bn_apply_kernel<<<dim3(16384), blk, 0, stream>>>(out, stats);
}

// Round 2
// 880.151 us; speedup vs baseline: 1.4047x; 1.0259x over previous
//
#include <hip/hip_runtime.h>
#include <math.h>

// Problem constants
#define BN 4
#define CC 256
#define HH_ 128
#define WW_ 128
#define HWP (HH_*WW_)           // 16384 pixels
#define TOK (64*HWP)            // 1,048,576 elems per (scale,batch) token matrix

// Workspace (bytes), total ~169.2 MB:
//  qt : bf16 [4 scale][4 b][tok][d]  33,554,432   (token-major, all scales)
//  kt : bf16 same                    33,554,432
//  vt : bf16 scales0-2 [d][tok], scale3 [tok][d]  33,554,432
//  aot: bf16 NHWC [b][y][x][c]       33,554,432   (attention out, conv input)
//  Sbf: bf16 score buffer (scales 1,2)  33,554,432
//  wpack: bf16 [256][9][256]          1,179,648
//  stats: 512 fp32 (conv sum/sumsq -> gs/gb)  2,048
//  S3 : fp32 [4][64][64]                 65,536
//  rs0: fp32 (unused, kept for layout)   65,536
//  rs1: fp32 [4][1024]                   16,384
//  rs2: fp32 [4][256]                     4,096
// Aliases: xt = Sbf (dead after proj), yt = aot (dead after proj).
// d_out scratch during attention: S2p (8 MB fp32 scale-2 K-split partials).

typedef __attribute__((ext_vector_type(8))) short bf16x8;
typedef __attribute__((ext_vector_type(4))) float f32x4;

__device__ __forceinline__ float bf2f(unsigned short u) {
    return __uint_as_float(((unsigned)u) << 16);
}
__device__ __forceinline__ unsigned short f2bf(float f) {
    unsigned u = __float_as_uint(f);
    u += 0x7FFF + ((u >> 16) & 1);
    return (unsigned short)(u >> 16);
}
__device__ __forceinline__ void load4f(const unsigned short* p, float o[4]) {
    ushort4 v = *(const ushort4*)p;
    o[0] = bf2f(v.x); o[1] = bf2f(v.y); o[2] = bf2f(v.z); o[3] = bf2f(v.w);
}
__device__ __forceinline__ float ld1(const unsigned short* p) { return bf2f(*p); }
__device__ __forceinline__ float ld1(const float* p) { return *p; }
__device__ __forceinline__ void st1(unsigned short* p, float v) { *p = f2bf(v); }
__device__ __forceinline__ void st1(float* p, float v) { *p = v; }

// ===========================================================================
// Shared MFMA tile machinery: block = 256 thr = 4 waves; tile M=128,N=128,BK=64
// LDS: As/Bs [128][72] bf16 (pad 8). Wave w covers 64x64 quadrant (wm,wn).
// ===========================================================================
#define LDS_STRIDE 72

struct Tile32 { uint4 v[4]; };   // 32 bf16 per thread per operand per BK-iter

__device__ __forceinline__ Tile32 load_tile_bf16(
    const unsigned short* src, size_t stride, int t)
{
    int r = t >> 1, kc = (t & 1) * 32;
    const uint4* sp = (const uint4*)(src + (size_t)r * stride + kc);
    Tile32 o;
    o.v[0] = sp[0]; o.v[1] = sp[1]; o.v[2] = sp[2]; o.v[3] = sp[3];
    return o;
}

__device__ __forceinline__ Tile32 load_tile_f32(
    const float* src, size_t stride, int t)
{
    int r = t >> 1, kc = (t & 1) * 32;
    const float4* sp = (const float4*)(src + (size_t)r * stride + kc);
    unsigned short tmp[32];
    #pragma unroll
    for (int i = 0; i < 8; i++) {
        float4 v = sp[i];
        tmp[i*4+0] = f2bf(v.x); tmp[i*4+1] = f2bf(v.y);
        tmp[i*4+2] = f2bf(v.z); tmp[i*4+3] = f2bf(v.w);
    }
    Tile32 o;
    const uint4* tp = (const uint4*)tmp;
    o.v[0] = tp[0]; o.v[1] = tp[1]; o.v[2] = tp[2]; o.v[3] = tp[3];
    return o;
}

__device__ __forceinline__ void store_tile(
    unsigned short* lds, const Tile32& d, int t)
{
    int r = t >> 1, kc = (t & 1) * 32;
    uint4* dp = (uint4*)&lds[r * LDS_STRIDE + kc];
    dp[0] = d.v[0]; dp[1] = d.v[1]; dp[2] = d.v[2]; dp[3] = d.v[3];
}

__device__ __forceinline__ void mfma_iter(
    const unsigned short* As, const unsigned short* Bs,
    int wm, int wn, int lr, int quad, f32x4 acc[4][4])
{
    #pragma unroll
    for (int s = 0; s < 2; s++) {
        bf16x8 af[4], bfr[4];
        #pragma unroll
        for (int i = 0; i < 4; i++)
            af[i] = *(const bf16x8*)&As[(wm*64 + i*16 + lr) * LDS_STRIDE + s*32 + quad*8];
        #pragma unroll
        for (int j = 0; j < 4; j++)
            bfr[j] = *(const bf16x8*)&Bs[(wn*64 + j*16 + lr) * LDS_STRIDE + s*32 + quad*8];
        #pragma unroll
        for (int i = 0; i < 4; i++)
            #pragma unroll
            for (int j = 0; j < 4; j++)
                acc[i][j] = __builtin_amdgcn_mfma_f32_16x16x32_bf16(
                    af[i], bfr[j], acc[i][j], 0, 0, 0);
    }
}

// ---------------------------------------------------------------------------
__global__ __launch_bounds__(256) void zero_kernel(float* __restrict__ p)
{
    p[blockIdx.x * 256 + threadIdx.x] = 0.f;
}

// ---------------------------------------------------------------------------
// NCHW fp32 -> NHWC bf16 for x and y. grid (256 p-tiles, 4 c-tiles, 8)
__global__ __launch_bounds__(256) void nchw_to_nhwc(
    const float* __restrict__ x, const float* __restrict__ y,
    unsigned short* __restrict__ xt, unsigned short* __restrict__ yt)
{
    __shared__ unsigned short T[64 * 72];
    int z = blockIdx.z;
    int b = z & 3, which = z >> 2;
    const float* src = (which ? y : x) + (size_t)b * CC * HWP;
    unsigned short* dst = (which ? yt : xt) + (size_t)b * HWP * CC;
    int p0 = blockIdx.x * 64, c0 = blockIdx.y * 64;
    int t = threadIdx.x;

    int cl = t >> 2, pc = (t & 3) * 16;
    #pragma unroll
    for (int e = 0; e < 16; e += 4) {
        float4 v = *(const float4*)&src[(size_t)(c0 + cl) * HWP + p0 + pc + e];
        T[(pc + e + 0) * 72 + cl] = f2bf(v.x);
        T[(pc + e + 1) * 72 + cl] = f2bf(v.y);
        T[(pc + e + 2) * 72 + cl] = f2bf(v.z);
        T[(pc + e + 3) * 72 + cl] = f2bf(v.w);
    }
    __syncthreads();
    int p = t >> 2, cc = (t & 3) * 16;
    uint4 a = *(uint4*)&T[p * 72 + cc];
    uint4 bsec = *(uint4*)&T[p * 72 + cc + 8];
    uint4* dp = (uint4*)&dst[(size_t)(p0 + p) * CC + c0 + cc];
    dp[0] = a; dp[1] = bsec;
}

// ---------------------------------------------------------------------------
// pack conv weights: Wo [o][c][3][3] fp32 -> wpack [o][tap][c] bf16
__global__ __launch_bounds__(256) void wpack_kernel(
    const float* __restrict__ Wo, unsigned short* __restrict__ wpack)
{
    int o = blockIdx.x, c = threadIdx.x;
    const float* wr = Wo + ((size_t)o * CC + c) * 9;
    #pragma unroll
    for (int tap = 0; tap < 9; tap++)
        wpack[((size_t)o * 9 + tap) * CC + c] = f2bf(wr[tap]);
}

// ---------------------------------------------------------------------------
// proj: C[o][p] = W[o][c] * X[p][c]^T + bias, scattered to token layouts.
// grid: (128 p-tiles, 2 o-tiles, 12) z = which*4 + b
__global__ __launch_bounds__(256) void proj_gemm(
    const unsigned short* __restrict__ xt, const unsigned short* __restrict__ yt,
    const float* __restrict__ Wq, const float* __restrict__ bq,
    const float* __restrict__ Wk, const float* __restrict__ bk,
    const float* __restrict__ Wv, const float* __restrict__ bv,
    unsigned short* __restrict__ qt, unsigned short* __restrict__ kt,
    unsigned short* __restrict__ vt)
{
    __shared__ unsigned short As[128 * LDS_STRIDE], Bs[128 * LDS_STRIDE];
    int z = blockIdx.z, b = z & 3, which = z >> 2;
    const unsigned short* src = (which == 0) ? xt : yt;
    const float* Wm   = (which == 0) ? Wq : (which == 1 ? Wk : Wv);
    const float* bias = (which == 0) ? bq : (which == 1 ? bk : bv);
    unsigned short* outp = (which == 0) ? qt : (which == 1 ? kt : vt);

    int m0 = blockIdx.y * 128;   // output channels
    int n0 = blockIdx.x * 128;   // pixels
    const float* A = Wm + (size_t)m0 * CC;
    const unsigned short* B = src + ((size_t)b * HWP + n0) * CC;

    int t = threadIdx.x, w = t >> 6, lane = t & 63;
    int quad = lane >> 4, lr = lane & 15, wm = w >> 1, wn = w & 1;

    f32x4 acc[4][4];
    #pragma unroll
    for (int i = 0; i < 4; i++)
        #pragma unroll
        for (int j = 0; j < 4; j++) acc[i][j] = (f32x4){0.f, 0.f, 0.f, 0.f};

    for (int k0 = 0; k0 < CC; k0 += 64) {
        Tile32 ta = load_tile_f32(A + k0, CC, t);
        Tile32 tb = load_tile_bf16(B + k0, CC, t);
        __syncthreads();
        store_tile(As, ta, t); store_tile(Bs, tb, t);
        __syncthreads();
        mfma_iter(As, Bs, wm, wn, lr, quad, acc);
    }

    #pragma unroll
    for (int i = 0; i < 4; i++) {
        int obase = m0 + wm * 64 + i * 16 + quad * 4;
        #pragma unroll
        for (int rr = 0; rr < 4; rr++) {
            int o = obase + rr;
            int s = o >> 6, lg = s + 1;
            int ch = o & 63;
            float bia = bias[o];
            unsigned short* ob = outp + ((size_t)s * 4 + b) * TOK;
            #pragma unroll
            for (int j = 0; j < 4; j++) {
                int p = n0 + wn * 64 + j * 16 + lr;
                int yy = p >> 7, xx = p & 127;
                int oy = yy >> lg, wy = yy & ((1 << lg) - 1);
                int ox = xx >> lg, wx = xx & ((1 << lg) - 1);
                int tokn = (oy << (7 - lg)) + ox;
                int didx = (ch << (2 * lg)) + (wy << lg) + wx;
                size_t idx;
                if (which == 2 && s < 3)
                    idx = ((size_t)didx << (14 - 2 * lg)) + tokn;   // [d][tok]
                else
                    idx = ((size_t)tokn << (6 + 2 * lg)) + didx;    // [tok][d]
                ob[idx] = f2bf(acc[i][j][rr] + bia);
            }
        }
    }
}

// ---------------------------------------------------------------------------
// Fused scale-0 attention (flash-style, no S materialization, no softmax max:
// scores ~N(0,1), exp safe in fp32). 512 thr = 8 waves (wm 0..1 x wn 0..3).
// Block: 64 q-tokens x all 4096 kv. grid 256 (XCD-swizzled: 2 XCDs per batch
// so K/V (4MB) stays L2-resident).
// Q frags in regs; K/V staged in Bs[256][72]; P in Ps[64][136].
#define PS_STRIDE 136

__global__ __launch_bounds__(512) void flash0(
    const unsigned short* __restrict__ qt, const unsigned short* __restrict__ kt,
    const unsigned short* __restrict__ vt, unsigned short* __restrict__ aot)
{
    __shared__ unsigned short Ps[64 * PS_STRIDE];     // 17.4 KB
    __shared__ unsigned short Bs[256 * LDS_STRIDE];   // 36.9 KB

    int L = blockIdx.x;
    int xcd = L & 7, slot = L >> 3;
    int b = xcd >> 1;
    int q0 = (slot + 32 * (xcd & 1)) * 64;

    const unsigned short* Qb = qt + (size_t)b * TOK;
    const unsigned short* Kb = kt + (size_t)b * TOK;
    const unsigned short* Vb = vt + (size_t)b * TOK;

    int t = threadIdx.x, w = t >> 6, lane = t & 63;
    int quad = lane >> 4, lr = lane & 15;
    int wm = w >> 2, wn = w & 3;

    // Q fragments (whole 64x256 tile, this wave's 32 rows): aq[k][s][i]
    bf16x8 aq[4][2][2];
    #pragma unroll
    for (int k = 0; k < 4; k++)
        #pragma unroll
        for (int s = 0; s < 2; s++)
            #pragma unroll
            for (int i = 0; i < 2; i++)
                aq[k][s][i] = *(const bf16x8*)&Qb[
                    (size_t)(q0 + wm*32 + i*16 + lr) * 256 + k*64 + s*32 + quad*8];

    f32x4 acc_o[2][4];
    #pragma unroll
    for (int i = 0; i < 2; i++)
        #pragma unroll
        for (int j = 0; j < 4; j++) acc_o[i][j] = (f32x4){0.f, 0.f, 0.f, 0.f};
    float rsum[2][4] = {};

    const float SC = 1.f / 16.f;
    int sr = t >> 1, sc_ = (t & 1) * 32;   // staging row/col (512 thr, 256 rows)

    for (int kv0 = 0; kv0 < 4096; kv0 += 128) {
        f32x4 acc_s[2][2];
        #pragma unroll
        for (int i = 0; i < 2; i++)
            #pragma unroll
            for (int j = 0; j < 2; j++) acc_s[i][j] = (f32x4){0.f, 0.f, 0.f, 0.f};

        // ---- S = Q K^T over d=256 in two staged pairs of BK=64 ----
        #pragma unroll
        for (int kp = 0; kp < 2; kp++) {
            __syncthreads();
            {   // stage 2 K-steps: Bs row r = (kstep sub)*128 + kv-local
                const uint4* sp = (const uint4*)&Kb[
                    (size_t)(kv0 + (sr & 127)) * 256 + kp*128 + (sr >> 7)*64 + sc_];
                uint4* dp = (uint4*)&Bs[sr * LDS_STRIDE + sc_];
                dp[0] = sp[0]; dp[1] = sp[1]; dp[2] = sp[2]; dp[3] = sp[3];
            }
            __syncthreads();
            #pragma unroll
            for (int t2 = 0; t2 < 2; t2++)
                #pragma unroll
                for (int s = 0; s < 2; s++) {
                    bf16x8 bfr[2];
                    #pragma unroll
                    for (int j = 0; j < 2; j++)
                        bfr[j] = *(const bf16x8*)&Bs[
                            (t2*128 + wn*32 + j*16 + lr) * LDS_STRIDE + s*32 + quad*8];
                    #pragma unroll
                    for (int i = 0; i < 2; i++)
                        #pragma unroll
                        for (int j = 0; j < 2; j++)
                            acc_s[i][j] = __builtin_amdgcn_mfma_f32_16x16x32_bf16(
                                aq[kp*2 + t2][s][i], bfr[j], acc_s[i][j], 0, 0, 0);
                }
        }

        // ---- exp, P -> LDS, rowsum accumulate ----
        #pragma unroll
        for (int i = 0; i < 2; i++)
            #pragma unroll
            for (int j = 0; j < 2; j++)
                #pragma unroll
                for (int rr = 0; rr < 4; rr++) {
                    float e = __expf(acc_s[i][j][rr] * SC);
                    Ps[(wm*32 + i*16 + quad*4 + rr) * PS_STRIDE + wn*32 + j*16 + lr]
                        = f2bf(e);
                    rsum[i][rr] += e;
                }

        // ---- O += P V  (V [d][tok]; two kv sub-steps of 64) ----
        #pragma unroll
        for (int ks = 0; ks < 2; ks++) {
            __syncthreads();   // Bs reads done + Ps writes visible
            {   // stage V [256 d][64 kv-slice]
                const uint4* sp = (const uint4*)&Vb[
                    (size_t)sr * 4096 + kv0 + ks*64 + sc_];
                uint4* dp = (uint4*)&Bs[sr * LDS_STRIDE + sc_];
                dp[0] = sp[0]; dp[1] = sp[1]; dp[2] = sp[2]; dp[3] = sp[3];
            }
            __syncthreads();
            #pragma unroll
            for (int s = 0; s < 2; s++) {
                bf16x8 pa[2], vb[4];
                #pragma unroll
                for (int i = 0; i < 2; i++)
                    pa[i] = *(const bf16x8*)&Ps[
                        (wm*32 + i*16 + lr) * PS_STRIDE + ks*64 + s*32 + quad*8];
                #pragma unroll
                for (int j = 0; j < 4; j++)
                    vb[j] = *(const bf16x8*)&Bs[
                        (wn*64 + j*16 + lr) * LDS_STRIDE + s*32 + quad*8];
                #pragma unroll
                for (int i = 0; i < 2; i++)
                    #pragma unroll
                    for (int j = 0; j < 4; j++)
                        acc_o[i][j] = __builtin_amdgcn_mfma_f32_16x16x32_bf16(
                            pa[i], vb[j], acc_o[i][j], 0, 0, 0);
            }
        }
    }

    // ---- rowsum block-reduce (reuse Ps as fp32 scratch), scale, store ----
    __syncthreads();
    float* rsred = (float*)Ps;   // [4 wn][64 tok]
    #pragma unroll
    for (int i = 0; i < 2; i++)
        #pragma unroll
        for (int rr = 0; rr < 4; rr++) {
            float v = rsum[i][rr];
            v += __shfl_xor(v, 1); v += __shfl_xor(v, 2);
            v += __shfl_xor(v, 4); v += __shfl_xor(v, 8);
            if (lr == 0)
                rsred[wn*64 + wm*32 + i*16 + quad*4 + rr] = v;
        }
    __syncthreads();
    #pragma unroll
    for (int i = 0; i < 2; i++)
        #pragma unroll
        for (int rr = 0; rr < 4; rr++) {
            int tl = wm*32 + i*16 + quad*4 + rr;
            float inv = 1.f / (rsred[tl] + rsred[64 + tl]
                             + rsred[128 + tl] + rsred[192 + tl]);
            int tokn = q0 + tl;
            int oy = tokn >> 6, ox = tokn & 63;
            #pragma unroll
            for (int j = 0; j < 4; j++) {
                int d = wn*64 + j*16 + lr;
                int ch = d >> 2, wp = d & 3;
                int yy = oy*2 + (wp >> 1), xx = ox*2 + (wp & 1);
                aot[((size_t)b * HWP + yy * WW_ + xx) * CC + ch]
                    = f2bf(acc_o[i][j][rr] * inv);
            }
        }
}

// ---------------------------------------------------------------------------
// E = exp(sc * Q K^T), plus per-row sums via shfl-reduce + atomicAdd.
// Q,K bf16 [tok][d]. grid: (NTOK/128, NTOK/128, nb) — scale 1.
template<int NTOK, int DD>
__global__ __launch_bounds__(256) void s_gemm_exp(
    const unsigned short* __restrict__ Qb, const unsigned short* __restrict__ Kb,
    unsigned short* __restrict__ S0, float* __restrict__ rsg, float sc)
{
    __shared__ unsigned short As[128 * LDS_STRIDE], Bs[128 * LDS_STRIDE];
    int bz = blockIdx.z;
    int m0 = blockIdx.y * 128, n0 = blockIdx.x * 128;
    const unsigned short* Q = Qb + (size_t)bz * TOK + (size_t)m0 * DD;
    const unsigned short* K = Kb + (size_t)bz * TOK + (size_t)n0 * DD;
    unsigned short* S = S0 + (size_t)bz * NTOK * NTOK;
    float* rs = rsg + (size_t)bz * NTOK;

    int t = threadIdx.x, w = t >> 6, lane = t & 63;
    int quad = lane >> 4, lr = lane & 15, wm = w >> 1, wn = w & 1;

    f32x4 acc[4][4];
    #pragma unroll
    for (int i = 0; i < 4; i++)
        #pragma unroll
        for (int j = 0; j < 4; j++) acc[i][j] = (f32x4){0.f, 0.f, 0.f, 0.f};

    for (int k0 = 0; k0 < DD; k0 += 64) {
        Tile32 ta = load_tile_bf16(Q + k0, DD, t);
        Tile32 tb = load_tile_bf16(K + k0, DD, t);
        __syncthreads();
        store_tile(As, ta, t); store_tile(Bs, tb, t);
        __syncthreads();
        mfma_iter(As, Bs, wm, wn, lr, quad, acc);
    }

    #pragma unroll
    for (int i = 0; i < 4; i++) {
        int m = m0 + wm * 64 + i * 16 + quad * 4;
        float rsum[4] = {0.f, 0.f, 0.f, 0.f};
        #pragma unroll
        for (int j = 0; j < 4; j++) {
            int n = n0 + wn * 64 + j * 16 + lr;
            #pragma unroll
            for (int rr = 0; rr < 4; rr++) {
                float e = __expf(acc[i][j][rr] * sc);
                S[(size_t)(m + rr) * NTOK + n] = f2bf(e);
                rsum[rr] += e;
            }
        }
        #pragma unroll
        for (int rr = 0; rr < 4; rr++) {
            float v = rsum[rr];
            v += __shfl_xor(v, 1);
            v += __shfl_xor(v, 2);
            v += __shfl_xor(v, 4);
            v += __shfl_xor(v, 8);
            if (lr == 0) atomicAdd(&rs[m + rr], v);
        }
    }
}

// ---------------------------------------------------------------------------
// O = E V with V stored [d][tok]; divides by rowsum; NHWC bf16 scatter.
// grid: (DD/128, NTOK/128, nb) — scales 1,2.
template<int NTOK, int DD, int LG, int CH0>
__global__ __launch_bounds__(256) void o_gemm(
    const unsigned short* __restrict__ Pb, const unsigned short* __restrict__ Vb,
    const float* __restrict__ rsg, unsigned short* __restrict__ aot, int b0)
{
    __shared__ unsigned short As[128 * LDS_STRIDE], Bs[128 * LDS_STRIDE];
    int bz = blockIdx.z, b = b0 + bz;
    int m0 = blockIdx.y * 128, n0 = blockIdx.x * 128;
    const unsigned short* P = Pb + (size_t)bz * NTOK * NTOK + (size_t)m0 * NTOK;
    const unsigned short* V = Vb + (size_t)bz * TOK + (size_t)n0 * NTOK;
    const float* rs = rsg + (size_t)bz * NTOK;

    int t = threadIdx.x, w = t >> 6, lane = t & 63;
    int quad = lane >> 4, lr = lane & 15, wm = w >> 1, wn = w & 1;

    f32x4 acc[4][4];
    #pragma unroll
    for (int i = 0; i < 4; i++)
        #pragma unroll
        for (int j = 0; j < 4; j++) acc[i][j] = (f32x4){0.f, 0.f, 0.f, 0.f};

    for (int k0 = 0; k0 < NTOK; k0 += 64) {
        Tile32 ta = load_tile_bf16(P + k0, NTOK, t);
        Tile32 tb = load_tile_bf16(V + k0, NTOK, t);
        __syncthreads();
        store_tile(As, ta, t); store_tile(Bs, tb, t);
        __syncthreads();
        mfma_iter(As, Bs, wm, wn, lr, quad, acc);
    }

    #pragma unroll
    for (int i = 0; i < 4; i++) {
        int tb0 = m0 + wm * 64 + i * 16 + quad * 4;
        #pragma unroll
        for (int rr = 0; rr < 4; rr++) {
            int tokn = tb0 + rr;
            float inv = 1.f / rs[tokn];
            int oy = tokn >> (7 - LG), ox = tokn & ((1 << (7 - LG)) - 1);
            #pragma unroll
            for (int j = 0; j < 4; j++) {
                int d = n0 + wn * 64 + j * 16 + lr;
                int ch = d >> (2 * LG);
                int r2 = d & ((1 << (2 * LG)) - 1);
                int wy = r2 >> LG, wx = r2 & ((1 << LG) - 1);
                int yy = (oy << LG) + wy, xx = (ox << LG) + wx;
                aot[((size_t)b * HWP + yy * WW_ + xx) * CC + CH0 + ch] =
                    f2bf(acc[i][j][rr] * inv);
            }
        }
    }
}

// ---------------------------------------------------------------------------
// Scale-2 score GEMM, 8-way K-split into fp32 partial buffers (d_out scratch).
// grid (2, 2, 32): z = b*8? no: b = z>>3, sp = z&7. K range sp*512..+512.
__global__ __launch_bounds__(256) void s2_partial(
    const unsigned short* __restrict__ Qb, const unsigned short* __restrict__ Kb,
    float* __restrict__ S2p)
{
    __shared__ unsigned short As[128 * LDS_STRIDE], Bs[128 * LDS_STRIDE];
    int z = blockIdx.z, b = z >> 3, sp = z & 7;
    int m0 = blockIdx.y * 128, n0 = blockIdx.x * 128;
    const unsigned short* Q = Qb + (size_t)b * TOK + (size_t)m0 * 4096;
    const unsigned short* K = Kb + (size_t)b * TOK + (size_t)n0 * 4096;
    float* So = S2p + ((size_t)(sp * 4 + b)) * 65536;

    int t = threadIdx.x, w = t >> 6, lane = t & 63;
    int quad = lane >> 4, lr = lane & 15, wm = w >> 1, wn = w & 1;

    f32x4 acc[4][4];
    #pragma unroll
    for (int i = 0; i < 4; i++)
        #pragma unroll
        for (int j = 0; j < 4; j++) acc[i][j] = (f32x4){0.f, 0.f, 0.f, 0.f};

    int kend = sp * 512 + 512;
    for (int k0 = sp * 512; k0 < kend; k0 += 64) {
        Tile32 ta = load_tile_bf16(Q + k0, 4096, t);
        Tile32 tb = load_tile_bf16(K + k0, 4096, t);
        __syncthreads();
        store_tile(As, ta, t); store_tile(Bs, tb, t);
        __syncthreads();
        mfma_iter(As, Bs, wm, wn, lr, quad, acc);
    }

    #pragma unroll
    for (int i = 0; i < 4; i++) {
        int m = m0 + wm * 64 + i * 16 + quad * 4;
        #pragma unroll
        for (int j = 0; j < 4; j++) {
            int n = n0 + wn * 64 + j * 16 + lr;
            #pragma unroll
            for (int rr = 0; rr < 4; rr++)
                So[(size_t)(m + rr) * 256 + n] = acc[i][j][rr];
        }
    }
}

// Sum 8 partials, exp, write bf16 S + rowsum. grid (256 rows, 4 b).
__global__ __launch_bounds__(256) void s2_finish(
    const float* __restrict__ S2p, unsigned short* __restrict__ Sbf,
    float* __restrict__ rs2, float sc)
{
    int row = blockIdx.x, b = blockIdx.y, t = threadIdx.x;
    float v = 0.f;
    #pragma unroll
    for (int sp = 0; sp < 8; sp++)
        v += S2p[((size_t)(sp * 4 + b)) * 65536 + row * 256 + t];
    float e = __expf(v * sc);
    Sbf[((size_t)b * 65536) + row * 256 + t] = f2bf(e);
    __shared__ float red[256];
    red[t] = e; __syncthreads();
    for (int s = 128; s > 0; s >>= 1) {
        if (t < s) red[t] += red[t + s];
        __syncthreads();
    }
    if (t == 0) rs2[b * 256 + row] = red[0];
}

// ---------------------------------------------------------------------------
// conv3x3 + fused BN-stats partials: out[o][p] = sum wpack*aot + bo;
// per-block per-o sum/sumsq -> atomicAdd stats[o], stats[256+o].
// grid: (128 y-rows, 2 o-tiles, 4 b)
__device__ __forceinline__ Tile32 load_tile_conv(
    const unsigned short* aob, int ys, int dx, int cbase, int t)
{
    int r = t >> 1, kc = (t & 1) * 32;
    int xs = r + dx;
    Tile32 o;
    if (ys >= 0 && ys < HH_ && xs >= 0 && xs < WW_) {
        const uint4* sp = (const uint4*)(aob + ((size_t)ys * WW_ + xs) * CC + cbase + kc);
        o.v[0] = sp[0]; o.v[1] = sp[1]; o.v[2] = sp[2]; o.v[3] = sp[3];
    } else {
        uint4 zz = make_uint4(0, 0, 0, 0);
        o.v[0] = zz; o.v[1] = zz; o.v[2] = zz; o.v[3] = zz;
    }
    return o;
}

__global__ __launch_bounds__(256) void conv_gemm(
    const unsigned short* __restrict__ aot, const unsigned short* __restrict__ wpack,
    const float* __restrict__ bo, float* __restrict__ zout,
    float* __restrict__ stats)
{
    __shared__ unsigned short As[128 * LDS_STRIDE], Bs[128 * LDS_STRIDE];
    int yrow = blockIdx.x;
    int o0 = blockIdx.y * 128;
    int b = blockIdx.z;
    const unsigned short* aob = aot + (size_t)b * HWP * CC;
    const unsigned short* wsrc = wpack + (size_t)o0 * 2304;

    int t = threadIdx.x, w = t >> 6, lane = t & 63;
    int quad = lane >> 4, lr = lane & 15, wm = w >> 1, wn = w & 1;

    f32x4 acc[4][4];
    #pragma unroll
    for (int i = 0; i < 4; i++)
        #pragma unroll
        for (int j = 0; j < 4; j++) acc[i][j] = (f32x4){0.f, 0.f, 0.f, 0.f};

    for (int tap = 0; tap < 9; tap++) {
        int dy = tap / 3 - 1, dx = tap % 3 - 1;
        int ys = yrow + dy;
        for (int cb = 0; cb < CC; cb += 64) {
            Tile32 ta = load_tile_bf16(wsrc + tap * CC + cb, 2304, t);
            Tile32 tb = load_tile_conv(aob, ys, dx, cb, t);
            __syncthreads();
            store_tile(As, ta, t); store_tile(Bs, tb, t);
            __syncthreads();
            mfma_iter(As, Bs, wm, wn, lr, quad, acc);
        }
    }

    #pragma unroll
    for (int i = 0; i < 4; i++) {
        #pragma unroll
        for (int rr = 0; rr < 4; rr++) {
            int o = o0 + wm * 64 + i * 16 + quad * 4 + rr;
            float bia = bo[o];
            float s1 = 0.f, s2v = 0.f;
            #pragma unroll
            for (int j = 0; j < 4; j++) {
                int x = wn * 64 + j * 16 + lr;
                float v = acc[i][j][rr] + bia;
                zout[((size_t)(b * CC + o)) * HWP + yrow * WW_ + x] = v;
                s1 += v; s2v = fmaf(v, v, s2v);
            }
            s1 += __shfl_xor(s1, 1); s2v += __shfl_xor(s2v, 1);
            s1 += __shfl_xor(s1, 2); s2v += __shfl_xor(s2v, 2);
            s1 += __shfl_xor(s1, 4); s2v += __shfl_xor(s2v, 4);
            s1 += __shfl_xor(s1, 8); s2v += __shfl_xor(s2v, 8);
            if (lr == 0) {
                atomicAdd(&stats[o], s1);
                atomicAdd(&stats[CC + o], s2v);
            }
        }
    }
}

// stats: [sum, sumsq] -> [gs, gb] in place. grid (1), 256 thr.
__global__ __launch_bounds__(256) void stats_finalize(
    float* __restrict__ stats, const float* __restrict__ gamma,
    const float* __restrict__ beta)
{
    int c = threadIdx.x;
    const float inv_n = 1.f / (BN * HWP);
    float mean = stats[c] * inv_n;
    float var = stats[CC + c] * inv_n - mean * mean;
    float rstd = rsqrtf(var + 1e-5f);
    float gs = gamma[c] * rstd;
    stats[c] = gs;
    stats[CC + c] = beta[c] - mean * gs;
}

// ---------------------------------------------------------------------------
// scale-3 S: N=64, D=16384, K-split 16, fp32 atomic acc. grid (1,1,64)
__global__ __launch_bounds__(256) void s3_kernel(
    const unsigned short* __restrict__ Qb, const unsigned short* __restrict__ Kb,
    float* __restrict__ S, float sc)
{
    const int N = 64, D = 16384, KLEN = 1024;
    int b = blockIdx.z >> 4, kc = blockIdx.z & 15;
    const unsigned short* Q = Qb + (size_t)b * TOK;
    const unsigned short* K = Kb + (size_t)b * TOK;
    float* Sb = S + (size_t)b * N * N;
    int k0 = kc * KLEN;

    __shared__ float As[16][64], Bs[16][64];
    int t = threadIdx.x, tx = t & 15, ty = t >> 4, r = t >> 2, q = t & 3;

    float acc[4][4] = {};
    for (int kk = k0; kk < k0 + KLEN; kk += 16) {
        float a4[4], b4[4];
        load4f(&Q[(size_t)r * D + kk + q * 4], a4);
        load4f(&K[(size_t)r * D + kk + q * 4], b4);
        __syncthreads();
        As[q*4+0][r] = a4[0]; As[q*4+1][r] = a4[1]; As[q*4+2][r] = a4[2]; As[q*4+3][r] = a4[3];
        Bs[q*4+0][r] = b4[0]; Bs[q*4+1][r] = b4[1]; Bs[q*4+2][r] = b4[2]; Bs[q*4+3][r] = b4[3];
        __syncthreads();
        #pragma unroll
        for (int k = 0; k < 16; k++) {
            float4 af = *(const float4*)&As[k][ty*4];
            float4 bf = *(const float4*)&Bs[k][tx*4];
            float ar[4] = {af.x, af.y, af.z, af.w};
            float br[4] = {bf.x, bf.y, bf.z, bf.w};
            #pragma unroll
            for (int ii = 0; ii < 4; ii++)
                #pragma unroll
                for (int jj = 0; jj < 4; jj++)
                    acc[ii][jj] = fmaf(ar[ii], br[jj], acc[ii][jj]);
        }
    }

    #pragma unroll
    for (int ii = 0; ii < 4; ii++)
        #pragma unroll
        for (int jj = 0; jj < 4; jj++)
            atomicAdd(&Sb[(size_t)(ty * 4 + ii) * N + tx * 4 + jj], acc[ii][jj] * sc);
}

// ---------------------------------------------------------------------------
// in-place row softmax (scale 3 only). grid: (n, nb)
template<typename T>
__global__ __launch_bounds__(256) void softmax_kernel(T* __restrict__ S, int n)
{
    int b = blockIdx.y;
    int row = blockIdx.x;
    T* rp = S + (size_t)b * n * n + (size_t)row * n;
    __shared__ float red[256];
    int t = threadIdx.x;

    float m = -1e30f;
    for (int j = t; j < n; j += 256) m = fmaxf(m, ld1(&rp[j]));
    red[t] = m; __syncthreads();
    for (int s = 128; s > 0; s >>= 1) { if (t < s) red[t] = fmaxf(red[t], red[t + s]); __syncthreads(); }
    m = red[0]; __syncthreads();

    float sum = 0.f;
    for (int j = t; j < n; j += 256) { float e = __expf(ld1(&rp[j]) - m); st1(&rp[j], e); sum += e; }
    red[t] = sum; __syncthreads();
    for (int s = 128; s > 0; s >>= 1) { if (t < s) red[t] += red[t + s]; __syncthreads(); }
    float inv = 1.f / red[0];
    for (int j = t; j < n; j += 256) st1(&rp[j], ld1(&rp[j]) * inv);
}

// ---------------------------------------------------------------------------
// scale-3 O = P(fp32 64x64) V(bf16 [tok][d]); NHWC bf16 out. grid (1,256,4)
__global__ __launch_bounds__(256) void o3_kernel(
    const float* __restrict__ P, const unsigned short* __restrict__ Vb,
    unsigned short* __restrict__ aot)
{
    const int N = 64, D = 16384, LG = 4, CH0 = 192;
    int bz = blockIdx.z;
    const float* Pb = P + (size_t)bz * N * N;
    const unsigned short* V = Vb + (size_t)bz * TOK;
    int i0 = blockIdx.x * 64, d0 = blockIdx.y * 64;

    __shared__ float Ps[16][64];
    __shared__ float Vs[16][64];
    int t = threadIdx.x, tx = t & 15, ty = t >> 4, r = t >> 2, q = t & 3;
    int vr = t >> 4, vq = t & 15;

    float acc[4][4] = {};
    for (int j0 = 0; j0 < N; j0 += 16) {
        float p4[4], v4[4];
        float4 pv = *(const float4*)&Pb[(size_t)(i0 + r) * N + j0 + q * 4];
        p4[0] = pv.x; p4[1] = pv.y; p4[2] = pv.z; p4[3] = pv.w;
        load4f(&V[(size_t)(j0 + vr) * D + d0 + vq * 4], v4);
        __syncthreads();
        Ps[q*4+0][r] = p4[0]; Ps[q*4+1][r] = p4[1]; Ps[q*4+2][r] = p4[2]; Ps[q*4+3][r] = p4[3];
        Vs[vr][vq*4+0] = v4[0]; Vs[vr][vq*4+1] = v4[1]; Vs[vr][vq*4+2] = v4[2]; Vs[vr][vq*4+3] = v4[3];
        __syncthreads();
        #pragma unroll
        for (int k = 0; k < 16; k++) {
            float4 pf = *(const float4*)&Ps[k][ty*4];
            float4 vf = *(const float4*)&Vs[k][tx*4];
            float pr[4] = {pf.x, pf.y, pf.z, pf.w};
            float vrr[4] = {vf.x, vf.y, vf.z, vf.w};
            #pragma unroll
            for (int ii = 0; ii < 4; ii++)
                #pragma unroll
                for (int jj = 0; jj < 4; jj++)
                    acc[ii][jj] = fmaf(pr[ii], vrr[jj], acc[ii][jj]);
        }
    }

    #pragma unroll
    for (int ii = 0; ii < 4; ii++) {
        int tokn = i0 + ty * 4 + ii;
        int oy = tokn >> (7 - LG), ox = tokn & ((1 << (7 - LG)) - 1);
        #pragma unroll
        for (int jj = 0; jj < 4; jj++) {
            int d = d0 + tx * 4 + jj;
            int ch = d >> (2 * LG);
            int r2 = d & ((1 << (2 * LG)) - 1);
            int wy = r2 >> LG, wx = r2 & ((1 << LG) - 1);
            int yy = (oy << LG) + wy, xx = (ox << LG) + wx;
            aot[((size_t)bz * HWP + yy * WW_ + xx) * CC + CH0 + ch] = f2bf(acc[ii][jj]);
        }
    }
}

// ---------------------------------------------------------------------------
__global__ __launch_bounds__(256) void bn_apply_kernel(
    float* __restrict__ z, const float* __restrict__ stats)
{
    size_t i4 = (size_t)blockIdx.x * 256 + threadIdx.x;
    size_t idx = i4 * 4;
    int c = (int)((idx >> 14) & 255);
    float gs = stats[c], gb = stats[CC + c];
    float4 v = *(float4*)&z[idx];
    v.x = fmaf(v.x, gs, gb); v.y = fmaf(v.y, gs, gb);
    v.z = fmaf(v.z, gs, gb); v.w = fmaf(v.w, gs, gb);
    v.x = v.x >= 0.f ? v.x : 0.2f * v.x;
    v.y = v.y >= 0.f ? v.y : 0.2f * v.y;
    v.z = v.z >= 0.f ? v.z : 0.2f * v.z;
    v.w = v.w >= 0.f ? v.w : 0.2f * v.w;
    *(float4*)&z[idx] = v;
}

// ---------------------------------------------------------------------------
extern "C" void kernel_launch(void* const* d_in, const int* in_sizes, int n_in,
                              void* d_out, int out_size, void* d_ws, size_t ws_size,
                              hipStream_t stream)
{
    const float* x     = (const float*)d_in[0];
    const float* y     = (const float*)d_in[1];
    const float* Wq    = (const float*)d_in[2];
    const float* bq    = (const float*)d_in[3];
    const float* Wk    = (const float*)d_in[4];
    const float* bk    = (const float*)d_in[5];
    const float* Wv    = (const float*)d_in[6];
    const float* bv    = (const float*)d_in[7];
    const float* Wo    = (const float*)d_in[8];
    const float* bo    = (const float*)d_in[9];
    const float* gamma = (const float*)d_in[10];
    const float* beta  = (const float*)d_in[11];
    float* out = (float*)d_out;

    unsigned short* qt    = (unsigned short*)d_ws;
    unsigned short* kt    = qt + (size_t)16777216;
    unsigned short* vt    = kt + (size_t)16777216;
    unsigned short* aot   = vt + (size_t)16777216;
    unsigned short* Sbf   = aot + (size_t)16777216;
    unsigned short* wpack = Sbf + (size_t)16777216;
    float* stats = (float*)(wpack + (size_t)589824);
    float* S3    = stats + 512;
    float* rs0   = S3 + 16384;     // unused (layout keep)
    float* rs1   = rs0 + 16384;    // [4][1024]
    float* rs2   = rs1 + 4096;     // [4][256]
    (void)rs0;
    // aliases (dead after proj_gemm):
    unsigned short* xt = Sbf;
    unsigned short* yt = aot;
    // d_out scratch during attention (dead until conv_gemm): scale-2 partials
    float* S2p = (float*)d_out;    // 8 * 4 * 65536 fp32 = 8 MB

    dim3 blk(256);

    // zero stats(512) + S3(16384) + rs0(16384) + rs1(4096) + rs2(1024) = 38400
    zero_kernel<<<dim3(150), blk, 0, stream>>>(stats);
    nchw_to_nhwc<<<dim3(256, 4, 8), blk, 0, stream>>>(x, y, xt, yt);
    wpack_kernel<<<dim3(256), blk, 0, stream>>>(Wo, wpack);

    proj_gemm<<<dim3(128, 2, 12), blk, 0, stream>>>(
        xt, yt, Wq, bq, Wk, bk, Wv, bv, qt, kt, vt);

    // scale 0: n=4096, D=256, window 2 — fully fused flash attention
    flash0<<<dim3(256), dim3(512), 0, stream>>>(qt, kt, vt, aot);

    // scale 1: n=1024, D=1024, window 4
    s_gemm_exp<1024, 1024><<<dim3(8, 8, 4), blk, 0, stream>>>(
        qt + (size_t)4 * TOK, kt + (size_t)4 * TOK, Sbf, rs1, 1.f / 32.f);
    o_gemm<1024, 1024, 2, 64><<<dim3(8, 8, 4), blk, 0, stream>>>(
        Sbf, vt + (size_t)4 * TOK, rs1, aot, 0);

    // scale 2: n=256, D=4096, window 8 — 8-way K-split into d_out scratch
    s2_partial<<<dim3(2, 2, 32), blk, 0, stream>>>(
        qt + (size_t)8 * TOK, kt + (size_t)8 * TOK, S2p);
    s2_finish<<<dim3(256, 4), blk, 0, stream>>>(S2p, Sbf, rs2, 1.f / 64.f);
    o_gemm<256, 4096, 3, 128><<<dim3(32, 2, 4), blk, 0, stream>>>(
        Sbf, vt + (size_t)8 * TOK, rs2, aot, 0);

    // scale 3: n=64, D=16384, window 16 — fp32 K-split path
    s3_kernel<<<dim3(1, 1, 64), blk, 0, stream>>>(
        qt + (size_t)12 * TOK, kt + (size_t)12 * TOK, S3, 1.f / 128.f);
    softmax_kernel<float><<<dim3(64, 4), blk, 0, stream>>>(S3, 64);
    o3_kernel<<<dim3(1, 256, 4), blk, 0, stream>>>(S3, vt + (size_t)12 * TOK, aot);

    // conv3x3 + fused BN stats, then finalize + apply
    conv_gemm<<<dim3(128, 2, 4), blk, 0, stream>>>(aot, wpack, bo, out, stats);
    stats_finalize<<<dim3(1), blk, 0, stream>>>(stats, gamma, beta);
    bn_apply_kernel<<<dim3(16384), blk, 0, stream>>>(out, stats);
}

// Round 3
// 870.501 us; speedup vs baseline: 1.4203x; 1.0111x over previous
//
#include <hip/hip_runtime.h>
#include <math.h>

// Problem constants
#define BN 4
#define CC 256
#define HH_ 128
#define WW_ 128
#define HWP (HH_*WW_)           // 16384 pixels
#define TOK (64*HWP)            // 1,048,576 elems per (scale,batch) token matrix

// Workspace layout (unchanged footprint ~169.1 MB):
//  qt, kt, vt, aot, Sbf : bf16, 33,554,432 B each
//  wpack: bf16 [256][9][256]          1,179,648 B
//  stats: 512 fp32; S3: fp32 [4][64][64]; rs0 [4][4096]; rs1 [4][1024]; rs2 [4][256]
// Aliases: xt = Sbf, yt = aot (dead after proj).
// d_out scratch: part (fp32 [2 kv-half][4 b][4096 tok][256 d] = 33.5 MB),
//   Wqkv_bf (bf16 [3][256][256], at d_out+33.5MB, dead before flash0),
//   S2p (8 MB, after part is dead).

typedef __attribute__((ext_vector_type(8))) short bf16x8;
typedef __attribute__((ext_vector_type(4))) float f32x4;

__device__ __forceinline__ float bf2f(unsigned short u) {
    return __uint_as_float(((unsigned)u) << 16);
}
__device__ __forceinline__ unsigned short f2bf(float f) {
    unsigned u = __float_as_uint(f);
    u += 0x7FFF + ((u >> 16) & 1);
    return (unsigned short)(u >> 16);
}
__device__ __forceinline__ void load4f(const unsigned short* p, float o[4]) {
    ushort4 v = *(const ushort4*)p;
    o[0] = bf2f(v.x); o[1] = bf2f(v.y); o[2] = bf2f(v.z); o[3] = bf2f(v.w);
}
__device__ __forceinline__ float ld1(const unsigned short* p) { return bf2f(*p); }
__device__ __forceinline__ float ld1(const float* p) { return *p; }
__device__ __forceinline__ void st1(unsigned short* p, float v) { *p = f2bf(v); }
__device__ __forceinline__ void st1(float* p, float v) { *p = v; }

// ===========================================================================
// NEW GEMM engine: 128x128 tile, BK=64, 256 thr = 4 waves.
// LDS: linear [128 rows][64 cols] bf16 per operand per buffer, double-buffered
// (64 KB). Staged via global_load_lds width-16 with XOR-swizzled SOURCE
// (slot ^= row&7 on 16B slots); ds_read applies the same XOR -> conflict-free.
// One __syncthreads per K-step (its vmcnt drain retires the prefetch issued
// before the MFMAs).
// ===========================================================================
__device__ __forceinline__ void gload16(const void* g, void* l) {
    __builtin_amdgcn_global_load_lds(
        (__attribute__((address_space(1))) void*)(g),
        (__attribute__((address_space(3))) void*)(l), 16, 0, 0);
}

// stage one 128x64 bf16 tile, row-major source with stride strideElems.
__device__ __forceinline__ void stage64(
    const unsigned short* src, size_t strideElems, unsigned short* lds, int t)
{
    #pragma unroll
    for (int k = 0; k < 4; k++) {
        int n = t + k * 256;              // 16B-segment id, 0..1023
        int row = n >> 3, slot = n & 7;
        const char* gp = (const char*)(src + (size_t)row * strideElems)
                       + ((slot ^ (row & 7)) << 4);
        gload16(gp, (char*)lds + n * 16);
    }
}

__device__ __forceinline__ void mfma_iter_swz(
    const unsigned short* As, const unsigned short* Bs,
    int wm, int wn, int lr, int quad, f32x4 acc[4][4])
{
    #pragma unroll
    for (int s = 0; s < 2; s++) {
        bf16x8 af[4], bfr[4];
        #pragma unroll
        for (int i = 0; i < 4; i++) {
            int row = wm*64 + i*16 + lr;
            int off = (row << 7) + (s << 6) + (quad << 4);
            af[i] = *(const bf16x8*)((const char*)As + (off ^ ((row & 7) << 4)));
        }
        #pragma unroll
        for (int j = 0; j < 4; j++) {
            int row = wn*64 + j*16 + lr;
            int off = (row << 7) + (s << 6) + (quad << 4);
            bfr[j] = *(const bf16x8*)((const char*)Bs + (off ^ ((row & 7) << 4)));
        }
        #pragma unroll
        for (int i = 0; i < 4; i++)
            #pragma unroll
            for (int j = 0; j < 4; j++)
                acc[i][j] = __builtin_amdgcn_mfma_f32_16x16x32_bf16(
                    af[i], bfr[j], acc[i][j], 0, 0, 0);
    }
}

// ===========================================================================
// OLD machinery (kept for conv_gemm only): pad-72 LDS, reg-staged.
// ===========================================================================
#define LDS_STRIDE 72

struct Tile32 { uint4 v[4]; };

__device__ __forceinline__ Tile32 load_tile_bf16(
    const unsigned short* src, size_t stride, int t)
{
    int r = t >> 1, kc = (t & 1) * 32;
    const uint4* sp = (const uint4*)(src + (size_t)r * stride + kc);
    Tile32 o;
    o.v[0] = sp[0]; o.v[1] = sp[1]; o.v[2] = sp[2]; o.v[3] = sp[3];
    return o;
}

__device__ __forceinline__ void store_tile(
    unsigned short* lds, const Tile32& d, int t)
{
    int r = t >> 1, kc = (t & 1) * 32;
    uint4* dp = (uint4*)&lds[r * LDS_STRIDE + kc];
    dp[0] = d.v[0]; dp[1] = d.v[1]; dp[2] = d.v[2]; dp[3] = d.v[3];
}

__device__ __forceinline__ void mfma_iter(
    const unsigned short* As, const unsigned short* Bs,
    int wm, int wn, int lr, int quad, f32x4 acc[4][4])
{
    #pragma unroll
    for (int s = 0; s < 2; s++) {
        bf16x8 af[4], bfr[4];
        #pragma unroll
        for (int i = 0; i < 4; i++)
            af[i] = *(const bf16x8*)&As[(wm*64 + i*16 + lr) * LDS_STRIDE + s*32 + quad*8];
        #pragma unroll
        for (int j = 0; j < 4; j++)
            bfr[j] = *(const bf16x8*)&Bs[(wn*64 + j*16 + lr) * LDS_STRIDE + s*32 + quad*8];
        #pragma unroll
        for (int i = 0; i < 4; i++)
            #pragma unroll
            for (int j = 0; j < 4; j++)
                acc[i][j] = __builtin_amdgcn_mfma_f32_16x16x32_bf16(
                    af[i], bfr[j], acc[i][j], 0, 0, 0);
    }
}

// ---------------------------------------------------------------------------
__global__ __launch_bounds__(256) void zero_kernel(float* __restrict__ p)
{
    p[blockIdx.x * 256 + threadIdx.x] = 0.f;
}

// ---------------------------------------------------------------------------
// NCHW fp32 -> NHWC bf16 for x and y. grid (256 p-tiles, 4 c-tiles, 8)
__global__ __launch_bounds__(256) void nchw_to_nhwc(
    const float* __restrict__ x, const float* __restrict__ y,
    unsigned short* __restrict__ xt, unsigned short* __restrict__ yt)
{
    __shared__ unsigned short T[64 * 72];
    int z = blockIdx.z;
    int b = z & 3, which = z >> 2;
    const float* src = (which ? y : x) + (size_t)b * CC * HWP;
    unsigned short* dst = (which ? yt : xt) + (size_t)b * HWP * CC;
    int p0 = blockIdx.x * 64, c0 = blockIdx.y * 64;
    int t = threadIdx.x;

    int cl = t >> 2, pc = (t & 3) * 16;
    #pragma unroll
    for (int e = 0; e < 16; e += 4) {
        float4 v = *(const float4*)&src[(size_t)(c0 + cl) * HWP + p0 + pc + e];
        T[(pc + e + 0) * 72 + cl] = f2bf(v.x);
        T[(pc + e + 1) * 72 + cl] = f2bf(v.y);
        T[(pc + e + 2) * 72 + cl] = f2bf(v.z);
        T[(pc + e + 3) * 72 + cl] = f2bf(v.w);
    }
    __syncthreads();
    int p = t >> 2, cc = (t & 3) * 16;
    uint4 a = *(uint4*)&T[p * 72 + cc];
    uint4 bsec = *(uint4*)&T[p * 72 + cc + 8];
    uint4* dp = (uint4*)&dst[(size_t)(p0 + p) * CC + c0 + cc];
    dp[0] = a; dp[1] = bsec;
}

// ---------------------------------------------------------------------------
// pack conv weights: Wo [o][c][3][3] fp32 -> wpack [o][tap][c] bf16
__global__ __launch_bounds__(256) void wpack_kernel(
    const float* __restrict__ Wo, unsigned short* __restrict__ wpack)
{
    int o = blockIdx.x, c = threadIdx.x;
    const float* wr = Wo + ((size_t)o * CC + c) * 9;
    #pragma unroll
    for (int tap = 0; tap < 9; tap++)
        wpack[((size_t)o * 9 + tap) * CC + c] = f2bf(wr[tap]);
}

// pack Wq/Wk/Wv fp32 [256][256] -> bf16 [3][256][256]. grid (3)
__global__ __launch_bounds__(256) void wqkv_pack(
    const float* __restrict__ Wq, const float* __restrict__ Wk,
    const float* __restrict__ Wv, unsigned short* __restrict__ Wb)
{
    int which = blockIdx.x;
    const float* W = which == 0 ? Wq : (which == 1 ? Wk : Wv);
    unsigned short* o = Wb + (size_t)which * 65536;
    for (int i = threadIdx.x; i < 65536; i += 256)
        o[i] = f2bf(W[i]);
}

// ---------------------------------------------------------------------------
// proj: C[o][p] = W[o][c] * X[p][c]^T + bias, scattered to token layouts.
// grid: (128 p-tiles, 2 o-tiles, 12) z = which*4 + b. New 2-phase engine.
__global__ __launch_bounds__(256) void proj_gemm(
    const unsigned short* __restrict__ xt, const unsigned short* __restrict__ yt,
    const unsigned short* __restrict__ Wqkv,
    const float* __restrict__ bq, const float* __restrict__ bk,
    const float* __restrict__ bv,
    unsigned short* __restrict__ qt, unsigned short* __restrict__ kt,
    unsigned short* __restrict__ vt)
{
    __shared__ unsigned short Asb[2][8192], Bsb[2][8192];
    int z = blockIdx.z, b = z & 3, which = z >> 2;
    const unsigned short* src = (which == 0) ? xt : yt;
    const float* bias = (which == 0) ? bq : (which == 1 ? bk : bv);
    unsigned short* outp = (which == 0) ? qt : (which == 1 ? kt : vt);

    int m0 = blockIdx.y * 128;   // output channels
    int n0 = blockIdx.x * 128;   // pixels
    const unsigned short* A = Wqkv + (size_t)which * 65536 + (size_t)m0 * CC;
    const unsigned short* B = src + ((size_t)b * HWP + n0) * CC;

    int t = threadIdx.x, w = t >> 6, lane = t & 63;
    int quad = lane >> 4, lr = lane & 15, wm = w >> 1, wn = w & 1;

    f32x4 acc[4][4];
    #pragma unroll
    for (int i = 0; i < 4; i++)
        #pragma unroll
        for (int j = 0; j < 4; j++) acc[i][j] = (f32x4){0.f, 0.f, 0.f, 0.f};

    stage64(A, CC, Asb[0], t);
    stage64(B, CC, Bsb[0], t);
    __syncthreads();
    int cur = 0;
    for (int k0 = 0; k0 < CC; k0 += 64) {
        if (k0 + 64 < CC) {
            stage64(A + k0 + 64, CC, Asb[cur ^ 1], t);
            stage64(B + k0 + 64, CC, Bsb[cur ^ 1], t);
        }
        mfma_iter_swz(Asb[cur], Bsb[cur], wm, wn, lr, quad, acc);
        __syncthreads();
        cur ^= 1;
    }

    #pragma unroll
    for (int i = 0; i < 4; i++) {
        int obase = m0 + wm * 64 + i * 16 + quad * 4;
        #pragma unroll
        for (int rr = 0; rr < 4; rr++) {
            int o = obase + rr;
            int s = o >> 6, lg = s + 1;
            int ch = o & 63;
            float bia = bias[o];
            unsigned short* ob = outp + ((size_t)s * 4 + b) * TOK;
            #pragma unroll
            for (int j = 0; j < 4; j++) {
                int p = n0 + wn * 64 + j * 16 + lr;
                int yy = p >> 7, xx = p & 127;
                int oy = yy >> lg, wy = yy & ((1 << lg) - 1);
                int ox = xx >> lg, wx = xx & ((1 << lg) - 1);
                int tokn = (oy << (7 - lg)) + ox;
                int didx = (ch << (2 * lg)) + (wy << lg) + wx;
                size_t idx;
                if (which == 2 && s < 3)
                    idx = ((size_t)didx << (14 - 2 * lg)) + tokn;   // [d][tok]
                else
                    idx = ((size_t)tokn << (6 + 2 * lg)) + didx;    // [tok][d]
                ob[idx] = f2bf(acc[i][j][rr] + bia);
            }
        }
    }
}

// ---------------------------------------------------------------------------
// Fused scale-0 attention, kv-split x2. 512 thr = 8 waves (wm 0..1 x wn 0..3).
// Block: 64 q-tokens x 2048 kv (half). grid 512, XCD-aware: 2 XCDs/batch,
// kv-half h pinned per XCD so each XCD's K/V slice (2MB) is L2-resident.
// Writes fp32 O-partial to part[(h*4+b)] + atomicAdd rowsums to rs0.
// K/V staged via global_load_lds into linear swizzled Bs[256][64].
#define PS_STRIDE 136

__global__ __launch_bounds__(512) void flash0(
    const unsigned short* __restrict__ qt, const unsigned short* __restrict__ kt,
    const unsigned short* __restrict__ vt, float* __restrict__ part,
    float* __restrict__ rs0g)
{
    __shared__ unsigned short Ps[64 * PS_STRIDE];   // 17.4 KB
    __shared__ unsigned short Bs[256 * 64];         // 32 KB linear swizzled

    int L = blockIdx.x;
    int xcd = L & 7, slot = L >> 3;
    int b = xcd >> 1;
    int idx = slot + 64 * (xcd & 1);
    int h = idx >> 6;
    int q0 = (idx & 63) * 64;
    int kvbase = h * 2048;

    const unsigned short* Qb = qt + (size_t)b * TOK;
    const unsigned short* Kb = kt + (size_t)b * TOK;
    const unsigned short* Vb = vt + (size_t)b * TOK;

    int t = threadIdx.x, w = t >> 6, lane = t & 63;
    int quad = lane >> 4, lr = lane & 15;
    int wm = w >> 2, wn = w & 3;

    // Q fragments (wave's 32 rows of the 64x256 Q tile): aq[k][s][i]
    bf16x8 aq[4][2][2];
    #pragma unroll
    for (int k = 0; k < 4; k++)
        #pragma unroll
        for (int s = 0; s < 2; s++)
            #pragma unroll
            for (int i = 0; i < 2; i++)
                aq[k][s][i] = *(const bf16x8*)&Qb[
                    (size_t)(q0 + wm*32 + i*16 + lr) * 256 + k*64 + s*32 + quad*8];

    f32x4 acc_o[2][4];
    #pragma unroll
    for (int i = 0; i < 2; i++)
        #pragma unroll
        for (int j = 0; j < 4; j++) acc_o[i][j] = (f32x4){0.f, 0.f, 0.f, 0.f};
    float rsum[2][4] = {};

    const float SC = 1.f / 16.f;

    for (int kv0 = kvbase; kv0 < kvbase + 2048; kv0 += 128) {
        f32x4 acc_s[2][2];
        #pragma unroll
        for (int i = 0; i < 2; i++)
            #pragma unroll
            for (int j = 0; j < 2; j++) acc_s[i][j] = (f32x4){0.f, 0.f, 0.f, 0.f};

        // ---- S = Q K^T over d=256 in two staged 128-d chunks ----
        #pragma unroll
        for (int kp = 0; kp < 2; kp++) {
            __syncthreads();
            #pragma unroll
            for (int k = 0; k < 4; k++) {
                int n = t + k * 512;
                int R = n >> 3, sl = n & 7;
                int kl = R & 127, dsub = R >> 7;
                const char* gp = (const char*)(Kb + (size_t)(kv0 + kl) * 256
                                 + kp*128 + dsub*64) + ((sl ^ (R & 7)) << 4);
                gload16(gp, (char*)Bs + n * 16);
            }
            __syncthreads();
            __builtin_amdgcn_s_setprio(1);
            #pragma unroll
            for (int t2 = 0; t2 < 2; t2++)
                #pragma unroll
                for (int s = 0; s < 2; s++) {
                    bf16x8 bfr[2];
                    #pragma unroll
                    for (int j = 0; j < 2; j++) {
                        int row = t2*128 + wn*32 + j*16 + lr;
                        int off = (row << 7) + (s << 6) + (quad << 4);
                        bfr[j] = *(const bf16x8*)((const char*)Bs
                                   + (off ^ ((row & 7) << 4)));
                    }
                    #pragma unroll
                    for (int i = 0; i < 2; i++)
                        #pragma unroll
                        for (int j = 0; j < 2; j++)
                            acc_s[i][j] = __builtin_amdgcn_mfma_f32_16x16x32_bf16(
                                aq[kp*2 + t2][s][i], bfr[j], acc_s[i][j], 0, 0, 0);
                }
            __builtin_amdgcn_s_setprio(0);
        }

        // ---- exp, P -> LDS, rowsum accumulate ----
        #pragma unroll
        for (int i = 0; i < 2; i++)
            #pragma unroll
            for (int j = 0; j < 2; j++)
                #pragma unroll
                for (int rr = 0; rr < 4; rr++) {
                    float e = __expf(acc_s[i][j][rr] * SC);
                    Ps[(wm*32 + i*16 + quad*4 + rr) * PS_STRIDE + wn*32 + j*16 + lr]
                        = f2bf(e);
                    rsum[i][rr] += e;
                }

        // ---- O += P V  (V [d][tok]; two kv sub-steps of 64) ----
        #pragma unroll
        for (int ks = 0; ks < 2; ks++) {
            __syncthreads();   // Bs reads done + Ps writes visible
            #pragma unroll
            for (int k = 0; k < 4; k++) {
                int n = t + k * 512;
                int R = n >> 3, sl = n & 7;
                const char* gp = (const char*)(Vb + (size_t)R * 4096 + kv0 + ks*64)
                               + ((sl ^ (R & 7)) << 4);
                gload16(gp, (char*)Bs + n * 16);
            }
            __syncthreads();
            __builtin_amdgcn_s_setprio(1);
            #pragma unroll
            for (int s = 0; s < 2; s++) {
                bf16x8 pa[2], vb[4];
                #pragma unroll
                for (int i = 0; i < 2; i++)
                    pa[i] = *(const bf16x8*)&Ps[
                        (wm*32 + i*16 + lr) * PS_STRIDE + ks*64 + s*32 + quad*8];
                #pragma unroll
                for (int j = 0; j < 4; j++) {
                    int row = wn*64 + j*16 + lr;
                    int off = (row << 7) + (s << 6) + (quad << 4);
                    vb[j] = *(const bf16x8*)((const char*)Bs
                              + (off ^ ((row & 7) << 4)));
                }
                #pragma unroll
                for (int i = 0; i < 2; i++)
                    #pragma unroll
                    for (int j = 0; j < 4; j++)
                        acc_o[i][j] = __builtin_amdgcn_mfma_f32_16x16x32_bf16(
                            pa[i], vb[j], acc_o[i][j], 0, 0, 0);
            }
            __builtin_amdgcn_s_setprio(0);
        }
    }

    // ---- epilogue: rowsum atomics + fp32 partial O store ----
    #pragma unroll
    for (int i = 0; i < 2; i++)
        #pragma unroll
        for (int rr = 0; rr < 4; rr++) {
            float v = rsum[i][rr];
            v += __shfl_xor(v, 1); v += __shfl_xor(v, 2);
            v += __shfl_xor(v, 4); v += __shfl_xor(v, 8);
            if (lr == 0)
                atomicAdd(&rs0g[b * 4096 + q0 + wm*32 + i*16 + quad*4 + rr], v);
        }
    float* op = part + ((size_t)(h * 4 + b)) * TOK;
    #pragma unroll
    for (int i = 0; i < 2; i++)
        #pragma unroll
        for (int rr = 0; rr < 4; rr++) {
            int tokl = wm*32 + i*16 + quad*4 + rr;
            float* orow = op + (size_t)(q0 + tokl) * 256;
            #pragma unroll
            for (int j = 0; j < 4; j++)
                orow[wn*64 + j*16 + lr] = acc_o[i][j][rr];
        }
}

// ---------------------------------------------------------------------------
// Sum 2 kv-half partials, divide by rowsum, scatter NHWC. grid (256, 4 b).
__global__ __launch_bounds__(256) void combine0f(
    const float* __restrict__ part, const float* __restrict__ rs,
    unsigned short* __restrict__ aot)
{
    int b = blockIdx.y;
    int tok0 = blockIdx.x * 16;
    const float* p0 = part + (size_t)b * TOK;
    const float* p1 = part + (size_t)(4 + b) * TOK;
    int t = threadIdx.x;
    int w = t >> 6, ch = t & 63;
    int wy = w >> 1, wx = w & 1;
    #pragma unroll 4
    for (int u = 0; u < 16; u++) {
        int tok = tok0 + u;
        size_t base = (size_t)tok * 256 + ch * 4 + w;
        float v = (p0[base] + p1[base]) * (1.f / rs[b * 4096 + tok]);
        int oy = tok >> 6, ox = tok & 63;
        int yy = oy * 2 + wy, xx = ox * 2 + wx;
        aot[((size_t)b * HWP + yy * WW_ + xx) * CC + ch] = f2bf(v);
    }
}

// ---------------------------------------------------------------------------
// E = exp(sc * Q K^T) + rowsum atomics. New 2-phase engine. Scale 1.
template<int NTOK, int DD>
__global__ __launch_bounds__(256) void s_gemm_exp(
    const unsigned short* __restrict__ Qb, const unsigned short* __restrict__ Kb,
    unsigned short* __restrict__ S0, float* __restrict__ rsg, float sc)
{
    __shared__ unsigned short Asb[2][8192], Bsb[2][8192];
    int bz = blockIdx.z;
    int m0 = blockIdx.y * 128, n0 = blockIdx.x * 128;
    const unsigned short* Q = Qb + (size_t)bz * TOK + (size_t)m0 * DD;
    const unsigned short* K = Kb + (size_t)bz * TOK + (size_t)n0 * DD;
    unsigned short* S = S0 + (size_t)bz * NTOK * NTOK;
    float* rs = rsg + (size_t)bz * NTOK;

    int t = threadIdx.x, w = t >> 6, lane = t & 63;
    int quad = lane >> 4, lr = lane & 15, wm = w >> 1, wn = w & 1;

    f32x4 acc[4][4];
    #pragma unroll
    for (int i = 0; i < 4; i++)
        #pragma unroll
        for (int j = 0; j < 4; j++) acc[i][j] = (f32x4){0.f, 0.f, 0.f, 0.f};

    stage64(Q, DD, Asb[0], t);
    stage64(K, DD, Bsb[0], t);
    __syncthreads();
    int cur = 0;
    for (int k0 = 0; k0 < DD; k0 += 64) {
        if (k0 + 64 < DD) {
            stage64(Q + k0 + 64, DD, Asb[cur ^ 1], t);
            stage64(K + k0 + 64, DD, Bsb[cur ^ 1], t);
        }
        mfma_iter_swz(Asb[cur], Bsb[cur], wm, wn, lr, quad, acc);
        __syncthreads();
        cur ^= 1;
    }

    #pragma unroll
    for (int i = 0; i < 4; i++) {
        int m = m0 + wm * 64 + i * 16 + quad * 4;
        float rsum[4] = {0.f, 0.f, 0.f, 0.f};
        #pragma unroll
        for (int j = 0; j < 4; j++) {
            int n = n0 + wn * 64 + j * 16 + lr;
            #pragma unroll
            for (int rr = 0; rr < 4; rr++) {
                float e = __expf(acc[i][j][rr] * sc);
                S[(size_t)(m + rr) * NTOK + n] = f2bf(e);
                rsum[rr] += e;
            }
        }
        #pragma unroll
        for (int rr = 0; rr < 4; rr++) {
            float v = rsum[rr];
            v += __shfl_xor(v, 1);
            v += __shfl_xor(v, 2);
            v += __shfl_xor(v, 4);
            v += __shfl_xor(v, 8);
            if (lr == 0) atomicAdd(&rs[m + rr], v);
        }
    }
}

// ---------------------------------------------------------------------------
// O = E V (V [d][tok]); divide by rowsum; NHWC scatter. New 2-phase engine.
template<int NTOK, int DD, int LG, int CH0>
__global__ __launch_bounds__(256) void o_gemm(
    const unsigned short* __restrict__ Pb, const unsigned short* __restrict__ Vb,
    const float* __restrict__ rsg, unsigned short* __restrict__ aot, int b0)
{
    __shared__ unsigned short Asb[2][8192], Bsb[2][8192];
    int bz = blockIdx.z, b = b0 + bz;
    int m0 = blockIdx.y * 128, n0 = blockIdx.x * 128;
    const unsigned short* P = Pb + (size_t)bz * NTOK * NTOK + (size_t)m0 * NTOK;
    const unsigned short* V = Vb + (size_t)bz * TOK + (size_t)n0 * NTOK;
    const float* rs = rsg + (size_t)bz * NTOK;

    int t = threadIdx.x, w = t >> 6, lane = t & 63;
    int quad = lane >> 4, lr = lane & 15, wm = w >> 1, wn = w & 1;

    f32x4 acc[4][4];
    #pragma unroll
    for (int i = 0; i < 4; i++)
        #pragma unroll
        for (int j = 0; j < 4; j++) acc[i][j] = (f32x4){0.f, 0.f, 0.f, 0.f};

    stage64(P, NTOK, Asb[0], t);
    stage64(V, NTOK, Bsb[0], t);
    __syncthreads();
    int cur = 0;
    for (int k0 = 0; k0 < NTOK; k0 += 64) {
        if (k0 + 64 < NTOK) {
            stage64(P + k0 + 64, NTOK, Asb[cur ^ 1], t);
            stage64(V + k0 + 64, NTOK, Bsb[cur ^ 1], t);
        }
        mfma_iter_swz(Asb[cur], Bsb[cur], wm, wn, lr, quad, acc);
        __syncthreads();
        cur ^= 1;
    }

    #pragma unroll
    for (int i = 0; i < 4; i++) {
        int tb0 = m0 + wm * 64 + i * 16 + quad * 4;
        #pragma unroll
        for (int rr = 0; rr < 4; rr++) {
            int tokn = tb0 + rr;
            float inv = 1.f / rs[tokn];
            int oy = tokn >> (7 - LG), ox = tokn & ((1 << (7 - LG)) - 1);
            #pragma unroll
            for (int j = 0; j < 4; j++) {
                int d = n0 + wn * 64 + j * 16 + lr;
                int ch = d >> (2 * LG);
                int r2 = d & ((1 << (2 * LG)) - 1);
                int wy = r2 >> LG, wx = r2 & ((1 << LG) - 1);
                int yy = (oy << LG) + wy, xx = (ox << LG) + wx;
                aot[((size_t)b * HWP + yy * WW_ + xx) * CC + CH0 + ch] =
                    f2bf(acc[i][j][rr] * inv);
            }
        }
    }
}

// ---------------------------------------------------------------------------
// Scale-2 score GEMM, 8-way K-split, fp32 partials. New 2-phase engine.
// grid (2, 2, 32): b = z>>3, sp = z&7.
__global__ __launch_bounds__(256) void s2_partial(
    const unsigned short* __restrict__ Qb, const unsigned short* __restrict__ Kb,
    float* __restrict__ S2p)
{
    __shared__ unsigned short Asb[2][8192], Bsb[2][8192];
    int z = blockIdx.z, b = z >> 3, sp = z & 7;
    int m0 = blockIdx.y * 128, n0 = blockIdx.x * 128;
    const unsigned short* Q = Qb + (size_t)b * TOK + (size_t)m0 * 4096 + sp * 512;
    const unsigned short* K = Kb + (size_t)b * TOK + (size_t)n0 * 4096 + sp * 512;
    float* So = S2p + ((size_t)(sp * 4 + b)) * 65536;

    int t = threadIdx.x, w = t >> 6, lane = t & 63;
    int quad = lane >> 4, lr = lane & 15, wm = w >> 1, wn = w & 1;

    f32x4 acc[4][4];
    #pragma unroll
    for (int i = 0; i < 4; i++)
        #pragma unroll
        for (int j = 0; j < 4; j++) acc[i][j] = (f32x4){0.f, 0.f, 0.f, 0.f};

    stage64(Q, 4096, Asb[0], t);
    stage64(K, 4096, Bsb[0], t);
    __syncthreads();
    int cur = 0;
    for (int k0 = 0; k0 < 512; k0 += 64) {
        if (k0 + 64 < 512) {
            stage64(Q + k0 + 64, 4096, Asb[cur ^ 1], t);
            stage64(K + k0 + 64, 4096, Bsb[cur ^ 1], t);
        }
        mfma_iter_swz(Asb[cur], Bsb[cur], wm, wn, lr, quad, acc);
        __syncthreads();
        cur ^= 1;
    }

    #pragma unroll
    for (int i = 0; i < 4; i++) {
        int m = m0 + wm * 64 + i * 16 + quad * 4;
        #pragma unroll
        for (int j = 0; j < 4; j++) {
            int n = n0 + wn * 64 + j * 16 + lr;
            #pragma unroll
            for (int rr = 0; rr < 4; rr++)
                So[(size_t)(m + rr) * 256 + n] = acc[i][j][rr];
        }
    }
}

// Sum 8 partials, exp, write bf16 S + rowsum. grid (256 rows, 4 b).
__global__ __launch_bounds__(256) void s2_finish(
    const float* __restrict__ S2p, unsigned short* __restrict__ Sbf,
    float* __restrict__ rs2, float sc)
{
    int row = blockIdx.x, b = blockIdx.y, t = threadIdx.x;
    float v = 0.f;
    #pragma unroll
    for (int sp = 0; sp < 8; sp++)
        v += S2p[((size_t)(sp * 4 + b)) * 65536 + row * 256 + t];
    float e = __expf(v * sc);
    Sbf[((size_t)b * 65536) + row * 256 + t] = f2bf(e);
    __shared__ float red[256];
    red[t] = e; __syncthreads();
    for (int s = 128; s > 0; s >>= 1) {
        if (t < s) red[t] += red[t + s];
        __syncthreads();
    }
    if (t == 0) rs2[b * 256 + row] = red[0];
}

// ---------------------------------------------------------------------------
// conv3x3 + fused BN-stats partials (old engine, boundary handling).
// grid: (128 y-rows, 2 o-tiles, 4 b)
__device__ __forceinline__ Tile32 load_tile_conv(
    const unsigned short* aob, int ys, int dx, int cbase, int t)
{
    int r = t >> 1, kc = (t & 1) * 32;
    int xs = r + dx;
    Tile32 o;
    if (ys >= 0 && ys < HH_ && xs >= 0 && xs < WW_) {
        const uint4* sp = (const uint4*)(aob + ((size_t)ys * WW_ + xs) * CC + cbase + kc);
        o.v[0] = sp[0]; o.v[1] = sp[1]; o.v[2] = sp[2]; o.v[3] = sp[3];
    } else {
        uint4 zz = make_uint4(0, 0, 0, 0);
        o.v[0] = zz; o.v[1] = zz; o.v[2] = zz; o.v[3] = zz;
    }
    return o;
}

__global__ __launch_bounds__(256) void conv_gemm(
    const unsigned short* __restrict__ aot, const unsigned short* __restrict__ wpack,
    const float* __restrict__ bo, float* __restrict__ zout,
    float* __restrict__ stats)
{
    __shared__ unsigned short As[128 * LDS_STRIDE], Bs[128 * LDS_STRIDE];
    int yrow = blockIdx.x;
    int o0 = blockIdx.y * 128;
    int b = blockIdx.z;
    const unsigned short* aob = aot + (size_t)b * HWP * CC;
    const unsigned short* wsrc = wpack + (size_t)o0 * 2304;

    int t = threadIdx.x, w = t >> 6, lane = t & 63;
    int quad = lane >> 4, lr = lane & 15, wm = w >> 1, wn = w & 1;

    f32x4 acc[4][4];
    #pragma unroll
    for (int i = 0; i < 4; i++)
        #pragma unroll
        for (int j = 0; j < 4; j++) acc[i][j] = (f32x4){0.f, 0.f, 0.f, 0.f};

    for (int tap = 0; tap < 9; tap++) {
        int dy = tap / 3 - 1, dx = tap % 3 - 1;
        int ys = yrow + dy;
        for (int cb = 0; cb < CC; cb += 64) {
            Tile32 ta = load_tile_bf16(wsrc + tap * CC + cb, 2304, t);
            Tile32 tb = load_tile_conv(aob, ys, dx, cb, t);
            __syncthreads();
            store_tile(As, ta, t); store_tile(Bs, tb, t);
            __syncthreads();
            mfma_iter(As, Bs, wm, wn, lr, quad, acc);
        }
    }

    #pragma unroll
    for (int i = 0; i < 4; i++) {
        #pragma unroll
        for (int rr = 0; rr < 4; rr++) {
            int o = o0 + wm * 64 + i * 16 + quad * 4 + rr;
            float bia = bo[o];
            float s1 = 0.f, s2v = 0.f;
            #pragma unroll
            for (int j = 0; j < 4; j++) {
                int x = wn * 64 + j * 16 + lr;
                float v = acc[i][j][rr] + bia;
                zout[((size_t)(b * CC + o)) * HWP + yrow * WW_ + x] = v;
                s1 += v; s2v = fmaf(v, v, s2v);
            }
            s1 += __shfl_xor(s1, 1); s2v += __shfl_xor(s2v, 1);
            s1 += __shfl_xor(s1, 2); s2v += __shfl_xor(s2v, 2);
            s1 += __shfl_xor(s1, 4); s2v += __shfl_xor(s2v, 4);
            s1 += __shfl_xor(s1, 8); s2v += __shfl_xor(s2v, 8);
            if (lr == 0) {
                atomicAdd(&stats[o], s1);
                atomicAdd(&stats[CC + o], s2v);
            }
        }
    }
}

// stats: [sum, sumsq] -> [gs, gb] in place. grid (1), 256 thr.
__global__ __launch_bounds__(256) void stats_finalize(
    float* __restrict__ stats, const float* __restrict__ gamma,
    const float* __restrict__ beta)
{
    int c = threadIdx.x;
    const float inv_n = 1.f / (BN * HWP);
    float mean = stats[c] * inv_n;
    float var = stats[CC + c] * inv_n - mean * mean;
    float rstd = rsqrtf(var + 1e-5f);
    float gs = gamma[c] * rstd;
    stats[c] = gs;
    stats[CC + c] = beta[c] - mean * gs;
}

// ---------------------------------------------------------------------------
// scale-3 S: N=64, D=16384, K-split 16, fp32 atomic acc. grid (1,1,64)
__global__ __launch_bounds__(256) void s3_kernel(
    const unsigned short* __restrict__ Qb, const unsigned short* __restrict__ Kb,
    float* __restrict__ S, float sc)
{
    const int N = 64, D = 16384, KLEN = 1024;
    int b = blockIdx.z >> 4, kc = blockIdx.z & 15;
    const unsigned short* Q = Qb + (size_t)b * TOK;
    const unsigned short* K = Kb + (size_t)b * TOK;
    float* Sb = S + (size_t)b * N * N;
    int k0 = kc * KLEN;

    __shared__ float As[16][64], Bs[16][64];
    int t = threadIdx.x, tx = t & 15, ty = t >> 4, r = t >> 2, q = t & 3;

    float acc[4][4] = {};
    for (int kk = k0; kk < k0 + KLEN; kk += 16) {
        float a4[4], b4[4];
        load4f(&Q[(size_t)r * D + kk + q * 4], a4);
        load4f(&K[(size_t)r * D + kk + q * 4], b4);
        __syncthreads();
        As[q*4+0][r] = a4[0]; As[q*4+1][r] = a4[1]; As[q*4+2][r] = a4[2]; As[q*4+3][r] = a4[3];
        Bs[q*4+0][r] = b4[0]; Bs[q*4+1][r] = b4[1]; Bs[q*4+2][r] = b4[2]; Bs[q*4+3][r] = b4[3];
        __syncthreads();
        #pragma unroll
        for (int k = 0; k < 16; k++) {
            float4 af = *(const float4*)&As[k][ty*4];
            float4 bf = *(const float4*)&Bs[k][tx*4];
            float ar[4] = {af.x, af.y, af.z, af.w};
            float br[4] = {bf.x, bf.y, bf.z, bf.w};
            #pragma unroll
            for (int ii = 0; ii < 4; ii++)
                #pragma unroll
                for (int jj = 0; jj < 4; jj++)
                    acc[ii][jj] = fmaf(ar[ii], br[jj], acc[ii][jj]);
        }
    }

    #pragma unroll
    for (int ii = 0; ii < 4; ii++)
        #pragma unroll
        for (int jj = 0; jj < 4; jj++)
            atomicAdd(&Sb[(size_t)(ty * 4 + ii) * N + tx * 4 + jj], acc[ii][jj] * sc);
}

// ---------------------------------------------------------------------------
// in-place row softmax (scale 3 only). grid: (n, nb)
template<typename T>
__global__ __launch_bounds__(256) void softmax_kernel(T* __restrict__ S, int n)
{
    int b = blockIdx.y;
    int row = blockIdx.x;
    T* rp = S + (size_t)b * n * n + (size_t)row * n;
    __shared__ float red[256];
    int t = threadIdx.x;

    float m = -1e30f;
    for (int j = t; j < n; j += 256) m = fmaxf(m, ld1(&rp[j]));
    red[t] = m; __syncthreads();
    for (int s = 128; s > 0; s >>= 1) { if (t < s) red[t] = fmaxf(red[t], red[t + s]); __syncthreads(); }
    m = red[0]; __syncthreads();

    float sum = 0.f;
    for (int j = t; j < n; j += 256) { float e = __expf(ld1(&rp[j]) - m); st1(&rp[j], e); sum += e; }
    red[t] = sum; __syncthreads();
    for (int s = 128; s > 0; s >>= 1) { if (t < s) red[t] += red[t + s]; __syncthreads(); }
    float inv = 1.f / red[0];
    for (int j = t; j < n; j += 256) st1(&rp[j], ld1(&rp[j]) * inv);
}

// ---------------------------------------------------------------------------
// scale-3 O = P(fp32 64x64) V(bf16 [tok][d]); NHWC bf16 out. grid (1,256,4)
__global__ __launch_bounds__(256) void o3_kernel(
    const float* __restrict__ P, const unsigned short* __restrict__ Vb,
    unsigned short* __restrict__ aot)
{
    const int N = 64, D = 16384, LG = 4, CH0 = 192;
    int bz = blockIdx.z;
    const float* Pb = P + (size_t)bz * N * N;
    const unsigned short* V = Vb + (size_t)bz * TOK;
    int i0 = blockIdx.x * 64, d0 = blockIdx.y * 64;

    __shared__ float Ps[16][64];
    __shared__ float Vs[16][64];
    int t = threadIdx.x, tx = t & 15, ty = t >> 4, r = t >> 2, q = t & 3;
    int vr = t >> 4, vq = t & 15;

    float acc[4][4] = {};
    for (int j0 = 0; j0 < N; j0 += 16) {
        float p4[4], v4[4];
        float4 pv = *(const float4*)&Pb[(size_t)(i0 + r) * N + j0 + q * 4];
        p4[0] = pv.x; p4[1] = pv.y; p4[2] = pv.z; p4[3] = pv.w;
        load4f(&V[(size_t)(j0 + vr) * D + d0 + vq * 4], v4);
        __syncthreads();
        Ps[q*4+0][r] = p4[0]; Ps[q*4+1][r] = p4[1]; Ps[q*4+2][r] = p4[2]; Ps[q*4+3][r] = p4[3];
        Vs[vr][vq*4+0] = v4[0]; Vs[vr][vq*4+1] = v4[1]; Vs[vr][vq*4+2] = v4[2]; Vs[vr][vq*4+3] = v4[3];
        __syncthreads();
        #pragma unroll
        for (int k = 0; k < 16; k++) {
            float4 pf = *(const float4*)&Ps[k][ty*4];
            float4 vf = *(const float4*)&Vs[k][tx*4];
            float pr[4] = {pf.x, pf.y, pf.z, pf.w};
            float vrr[4] = {vf.x, vf.y, vf.z, vf.w};
            #pragma unroll
            for (int ii = 0; ii < 4; ii++)
                #pragma unroll
                for (int jj = 0; jj < 4; jj++)
                    acc[ii][jj] = fmaf(pr[ii], vrr[jj], acc[ii][jj]);
        }
    }

    #pragma unroll
    for (int ii = 0; ii < 4; ii++) {
        int tokn = i0 + ty * 4 + ii;
        int oy = tokn >> (7 - LG), ox = tokn & ((1 << (7 - LG)) - 1);
        #pragma unroll
        for (int jj = 0; jj < 4; jj++) {
            int d = d0 + tx * 4 + jj;
            int ch = d >> (2 * LG);
            int r2 = d & ((1 << (2 * LG)) - 1);
            int wy = r2 >> LG, wx = r2 & ((1 << LG) - 1);
            int yy = (oy << LG) + wy, xx = (ox << LG) + wx;
            aot[((size_t)bz * HWP + yy * WW_ + xx) * CC + CH0 + ch] = f2bf(acc[ii][jj]);
        }
    }
}

// ---------------------------------------------------------------------------
__global__ __launch_bounds__(256) void bn_apply_kernel(
    float* __restrict__ z, const float* __restrict__ stats)
{
    size_t i4 = (size_t)blockIdx.x * 256 + threadIdx.x;
    size_t idx = i4 * 4;
    int c = (int)((idx >> 14) & 255);
    float gs = stats[c], gb = stats[CC + c];
    float4 v = *(float4*)&z[idx];
    v.x = fmaf(v.x, gs, gb); v.y = fmaf(v.y, gs, gb);
    v.z = fmaf(v.z, gs, gb); v.w = fmaf(v.w, gs, gb);
    v.x = v.x >= 0.f ? v.x : 0.2f * v.x;
    v.y = v.y >= 0.f ? v.y : 0.2f * v.y;
    v.z = v.z >= 0.f ? v.z : 0.2f * v.z;
    v.w = v.w >= 0.f ? v.w : 0.2f * v.w;
    *(float4*)&z[idx] = v;
}

// ---------------------------------------------------------------------------
extern "C" void kernel_launch(void* const* d_in, const int* in_sizes, int n_in,
                              void* d_out, int out_size, void* d_ws, size_t ws_size,
                              hipStream_t stream)
{
    const float* x     = (const float*)d_in[0];
    const float* y     = (const float*)d_in[1];
    const float* Wq    = (const float*)d_in[2];
    const float* bq    = (const float*)d_in[3];
    const float* Wk    = (const float*)d_in[4];
    const float* bk    = (const float*)d_in[5];
    const float* Wv    = (const float*)d_in[6];
    const float* bv    = (const float*)d_in[7];
    const float* Wo    = (const float*)d_in[8];
    const float* bo    = (const float*)d_in[9];
    const float* gamma = (const float*)d_in[10];
    const float* beta  = (const float*)d_in[11];
    float* out = (float*)d_out;

    unsigned short* qt    = (unsigned short*)d_ws;
    unsigned short* kt    = qt + (size_t)16777216;
    unsigned short* vt    = kt + (size_t)16777216;
    unsigned short* aot   = vt + (size_t)16777216;
    unsigned short* Sbf   = aot + (size_t)16777216;
    unsigned short* wpack = Sbf + (size_t)16777216;
    float* stats = (float*)(wpack + (size_t)589824);
    float* S3    = stats + 512;
    float* rs0   = S3 + 16384;     // [4][4096] scale-0 rowsums
    float* rs1   = rs0 + 16384;    // [4][1024]
    float* rs2   = rs1 + 4096;     // [4][256]
    // aliases (dead after proj_gemm):
    unsigned short* xt = Sbf;
    unsigned short* yt = aot;
    // d_out scratch:
    float* part = (float*)d_out;                                   // 33.5 MB
    unsigned short* Wqkv_bf = (unsigned short*)((char*)d_out + (size_t)33554432);
    float* S2p = (float*)d_out;    // scale-2 partials (after part is dead)

    dim3 blk(256);

    // zero stats(512)+S3(16384)+rs0(16384)+rs1(4096)+rs2(1024) = 38400 floats
    zero_kernel<<<dim3(150), blk, 0, stream>>>(stats);
    nchw_to_nhwc<<<dim3(256, 4, 8), blk, 0, stream>>>(x, y, xt, yt);
    wpack_kernel<<<dim3(256), blk, 0, stream>>>(Wo, wpack);
    wqkv_pack<<<dim3(3), blk, 0, stream>>>(Wq, Wk, Wv, Wqkv_bf);

    proj_gemm<<<dim3(128, 2, 12), blk, 0, stream>>>(
        xt, yt, Wqkv_bf, bq, bk, bv, qt, kt, vt);

    // scale 0: n=4096, D=256, window 2 — fused flash, kv-split x2
    flash0<<<dim3(512), dim3(512), 0, stream>>>(qt, kt, vt, part, rs0);
    combine0f<<<dim3(256, 4), blk, 0, stream>>>(part, rs0, aot);

    // scale 1: n=1024, D=1024, window 4
    s_gemm_exp<1024, 1024><<<dim3(8, 8, 4), blk, 0, stream>>>(
        qt + (size_t)4 * TOK, kt + (size_t)4 * TOK, Sbf, rs1, 1.f / 32.f);
    o_gemm<1024, 1024, 2, 64><<<dim3(8, 8, 4), blk, 0, stream>>>(
        Sbf, vt + (size_t)4 * TOK, rs1, aot, 0);

    // scale 2: n=256, D=4096, window 8 — 8-way K-split into d_out scratch
    s2_partial<<<dim3(2, 2, 32), blk, 0, stream>>>(
        qt + (size_t)8 * TOK, kt + (size_t)8 * TOK, S2p);
    s2_finish<<<dim3(256, 4), blk, 0, stream>>>(S2p, Sbf, rs2, 1.f / 64.f);
    o_gemm<256, 4096, 3, 128><<<dim3(32, 2, 4), blk, 0, stream>>>(
        Sbf, vt + (size_t)8 * TOK, rs2, aot, 0);

    // scale 3: n=64, D=16384, window 16 — fp32 K-split path
    s3_kernel<<<dim3(1, 1, 64), blk, 0, stream>>>(
        qt + (size_t)12 * TOK, kt + (size_t)12 * TOK, S3, 1.f / 128.f);
    softmax_kernel<float><<<dim3(64, 4), blk, 0, stream>>>(S3, 64);
    o3_kernel<<<dim3(1, 256, 4), blk, 0, stream>>>(S3, vt + (size_t)12 * TOK, aot);

    // conv3x3 + fused BN stats, then finalize + apply
    conv_gemm<<<dim3(128, 2, 4), blk, 0, stream>>>(aot, wpack, bo, out, stats);
    stats_finalize<<<dim3(1), blk, 0, stream>>>(stats, gamma, beta);
    bn_apply_kernel<<<dim3(16384), blk, 0, stream>>>(out, stats);
}

// Round 4
// 851.930 us; speedup vs baseline: 1.4512x; 1.0218x over previous
//
#include <hip/hip_runtime.h>
#include <math.h>

// Problem constants
#define BN 4
#define CC 256
#define HH_ 128
#define WW_ 128
#define HWP (HH_*WW_)           // 16384 pixels
#define TOK (64*HWP)            // 1,048,576 elems per (scale,batch) token matrix

// Workspace layout (~145.4 MB used):
//  qt, kt, vt : bf16 33,554,432 B each
//  aotp: bf16 padded NHWC [4][130][130][256] = 34,611,200 B (1-px zero halo)
//  Sbf : bf16 scale-1/2 score buffer 8,388,608 B
//  wpack: bf16 [256][9][256] 1,179,648 B
//  Wqkv: bf16 [3][256][256] 393,216 B
//  stats(512) S3(16384) rs0(16384) rs1(4096) rs2(1024) fp32 = 153,600 B
// d_out scratch (67 MB, dead until conv writes it):
//  phase A: xt [0,33.5M), yt [33.5M,67M)  (NHWC bf16 inputs for proj)
//  phase B: part [0,33.5M) flash0 fp32 partials; then S2p [0,8M).

typedef __attribute__((ext_vector_type(8))) short bf16x8;
typedef __attribute__((ext_vector_type(4))) float f32x4;

__device__ __forceinline__ float bf2f(unsigned short u) {
    return __uint_as_float(((unsigned)u) << 16);
}
__device__ __forceinline__ unsigned short f2bf(float f) {
    unsigned u = __float_as_uint(f);
    u += 0x7FFF + ((u >> 16) & 1);
    return (unsigned short)(u >> 16);
}
__device__ __forceinline__ float ld1(const float* p) { return *p; }
__device__ __forceinline__ void st1(float* p, float v) { *p = v; }

// ===========================================================================
// GEMM engine: 128x128 tile, BK=64, 256 thr = 4 waves.
// LDS: linear [128 rows][64 cols] bf16 per operand per buffer, double-buffered.
// Staged via global_load_lds width-16 with XOR-swizzled SOURCE (slot ^= row&7
// on 16B slots); ds_read applies the same XOR -> conflict-free.
// One __syncthreads per K-step (its vmcnt drain retires the prefetch issued
// before the MFMAs).
// ===========================================================================
__device__ __forceinline__ void gload16(const void* g, void* l) {
    __builtin_amdgcn_global_load_lds(
        (__attribute__((address_space(1))) void*)(g),
        (__attribute__((address_space(3))) void*)(l), 16, 0, 0);
}

// stage one 128x64 bf16 tile, row-major source with stride strideElems.
__device__ __forceinline__ void stage64(
    const unsigned short* src, size_t strideElems, unsigned short* lds, int t)
{
    #pragma unroll
    for (int k = 0; k < 4; k++) {
        int n = t + k * 256;              // 16B-segment id, 0..1023
        int row = n >> 3, slot = n & 7;
        const char* gp = (const char*)(src + (size_t)row * strideElems)
                       + ((slot ^ (row & 7)) << 4);
        gload16(gp, (char*)lds + n * 16);
    }
}

// stage one 64x64 bf16 tile (half-height).
__device__ __forceinline__ void stage32(
    const unsigned short* src, size_t strideElems, unsigned short* lds, int t)
{
    #pragma unroll
    for (int k = 0; k < 2; k++) {
        int n = t + k * 256;              // 0..511
        int row = n >> 3, slot = n & 7;
        const char* gp = (const char*)(src + (size_t)row * strideElems)
                       + ((slot ^ (row & 7)) << 4);
        gload16(gp, (char*)lds + n * 16);
    }
}

__device__ __forceinline__ void mfma_iter_swz(
    const unsigned short* As, const unsigned short* Bs,
    int wm, int wn, int lr, int quad, f32x4 acc[4][4])
{
    #pragma unroll
    for (int s = 0; s < 2; s++) {
        bf16x8 af[4], bfr[4];
        #pragma unroll
        for (int i = 0; i < 4; i++) {
            int row = wm*64 + i*16 + lr;
            int off = (row << 7) + (s << 6) + (quad << 4);
            af[i] = *(const bf16x8*)((const char*)As + (off ^ ((row & 7) << 4)));
        }
        #pragma unroll
        for (int j = 0; j < 4; j++) {
            int row = wn*64 + j*16 + lr;
            int off = (row << 7) + (s << 6) + (quad << 4);
            bfr[j] = *(const bf16x8*)((const char*)Bs + (off ^ ((row & 7) << 4)));
        }
        #pragma unroll
        for (int i = 0; i < 4; i++)
            #pragma unroll
            for (int j = 0; j < 4; j++)
                acc[i][j] = __builtin_amdgcn_mfma_f32_16x16x32_bf16(
                    af[i], bfr[j], acc[i][j], 0, 0, 0);
    }
}

// ---------------------------------------------------------------------------
__global__ __launch_bounds__(256) void zero_kernel(float* __restrict__ p)
{
    p[blockIdx.x * 256 + threadIdx.x] = 0.f;
}

__global__ __launch_bounds__(256) void zero4(uint4* __restrict__ p, int n4)
{
    uint4 z = make_uint4(0, 0, 0, 0);
    for (int i = blockIdx.x * 256 + threadIdx.x; i < n4; i += gridDim.x * 256)
        p[i] = z;
}

// ---------------------------------------------------------------------------
// NCHW fp32 -> NHWC bf16 for x and y. grid (256 p-tiles, 4 c-tiles, 8)
__global__ __launch_bounds__(256) void nchw_to_nhwc(
    const float* __restrict__ x, const float* __restrict__ y,
    unsigned short* __restrict__ xt, unsigned short* __restrict__ yt)
{
    __shared__ unsigned short T[64 * 72];
    int z = blockIdx.z;
    int b = z & 3, which = z >> 2;
    const float* src = (which ? y : x) + (size_t)b * CC * HWP;
    unsigned short* dst = (which ? yt : xt) + (size_t)b * HWP * CC;
    int p0 = blockIdx.x * 64, c0 = blockIdx.y * 64;
    int t = threadIdx.x;

    int cl = t >> 2, pc = (t & 3) * 16;
    #pragma unroll
    for (int e = 0; e < 16; e += 4) {
        float4 v = *(const float4*)&src[(size_t)(c0 + cl) * HWP + p0 + pc + e];
        T[(pc + e + 0) * 72 + cl] = f2bf(v.x);
        T[(pc + e + 1) * 72 + cl] = f2bf(v.y);
        T[(pc + e + 2) * 72 + cl] = f2bf(v.z);
        T[(pc + e + 3) * 72 + cl] = f2bf(v.w);
    }
    __syncthreads();
    int p = t >> 2, cc = (t & 3) * 16;
    uint4 a = *(uint4*)&T[p * 72 + cc];
    uint4 bsec = *(uint4*)&T[p * 72 + cc + 8];
    uint4* dp = (uint4*)&dst[(size_t)(p0 + p) * CC + c0 + cc];
    dp[0] = a; dp[1] = bsec;
}

// ---------------------------------------------------------------------------
// pack conv weights: Wo [o][c][3][3] fp32 -> wpack [o][tap][c] bf16
__global__ __launch_bounds__(256) void wpack_kernel(
    const float* __restrict__ Wo, unsigned short* __restrict__ wpack)
{
    int o = blockIdx.x, c = threadIdx.x;
    const float* wr = Wo + ((size_t)o * CC + c) * 9;
    #pragma unroll
    for (int tap = 0; tap < 9; tap++)
        wpack[((size_t)o * 9 + tap) * CC + c] = f2bf(wr[tap]);
}

// pack Wq/Wk/Wv fp32 [256][256] -> bf16 [3][256][256]. grid (3)
__global__ __launch_bounds__(256) void wqkv_pack(
    const float* __restrict__ Wq, const float* __restrict__ Wk,
    const float* __restrict__ Wv, unsigned short* __restrict__ Wb)
{
    int which = blockIdx.x;
    const float* W = which == 0 ? Wq : (which == 1 ? Wk : Wv);
    unsigned short* o = Wb + (size_t)which * 65536;
    for (int i = threadIdx.x; i < 65536; i += 256)
        o[i] = f2bf(W[i]);
}

// ---------------------------------------------------------------------------
// proj: C[o][p] = W[o][c] * X[p][c]^T + bias, scattered to token layouts.
// grid: (128 p-tiles, 2 o-tiles, 12) z = which*4 + b.
__global__ __launch_bounds__(256) void proj_gemm(
    const unsigned short* __restrict__ xt, const unsigned short* __restrict__ yt,
    const unsigned short* __restrict__ Wqkv,
    const float* __restrict__ bq, const float* __restrict__ bk,
    const float* __restrict__ bv,
    unsigned short* __restrict__ qt, unsigned short* __restrict__ kt,
    unsigned short* __restrict__ vt)
{
    __shared__ unsigned short Asb[2][8192], Bsb[2][8192];
    int z = blockIdx.z, b = z & 3, which = z >> 2;
    const unsigned short* src = (which == 0) ? xt : yt;
    const float* bias = (which == 0) ? bq : (which == 1 ? bk : bv);
    unsigned short* outp = (which == 0) ? qt : (which == 1 ? kt : vt);

    int m0 = blockIdx.y * 128;   // output channels
    int n0 = blockIdx.x * 128;   // pixels
    const unsigned short* A = Wqkv + (size_t)which * 65536 + (size_t)m0 * CC;
    const unsigned short* B = src + ((size_t)b * HWP + n0) * CC;

    int t = threadIdx.x, w = t >> 6, lane = t & 63;
    int quad = lane >> 4, lr = lane & 15, wm = w >> 1, wn = w & 1;

    f32x4 acc[4][4];
    #pragma unroll
    for (int i = 0; i < 4; i++)
        #pragma unroll
        for (int j = 0; j < 4; j++) acc[i][j] = (f32x4){0.f, 0.f, 0.f, 0.f};

    stage64(A, CC, Asb[0], t);
    stage64(B, CC, Bsb[0], t);
    __syncthreads();
    int cur = 0;
    for (int k0 = 0; k0 < CC; k0 += 64) {
        if (k0 + 64 < CC) {
            stage64(A + k0 + 64, CC, Asb[cur ^ 1], t);
            stage64(B + k0 + 64, CC, Bsb[cur ^ 1], t);
        }
        mfma_iter_swz(Asb[cur], Bsb[cur], wm, wn, lr, quad, acc);
        __syncthreads();
        cur ^= 1;
    }

    #pragma unroll
    for (int i = 0; i < 4; i++) {
        int obase = m0 + wm * 64 + i * 16 + quad * 4;
        #pragma unroll
        for (int rr = 0; rr < 4; rr++) {
            int o = obase + rr;
            int s = o >> 6, lg = s + 1;
            int ch = o & 63;
            float bia = bias[o];
            unsigned short* ob = outp + ((size_t)s * 4 + b) * TOK;
            #pragma unroll
            for (int j = 0; j < 4; j++) {
                int p = n0 + wn * 64 + j * 16 + lr;
                int yy = p >> 7, xx = p & 127;
                int oy = yy >> lg, wy = yy & ((1 << lg) - 1);
                int ox = xx >> lg, wx = xx & ((1 << lg) - 1);
                int tokn = (oy << (7 - lg)) + ox;
                int didx = (ch << (2 * lg)) + (wy << lg) + wx;
                size_t idx;
                if (which == 2)
                    idx = ((size_t)didx << (14 - 2 * lg)) + tokn;   // [d][tok]
                else
                    idx = ((size_t)tokn << (6 + 2 * lg)) + didx;    // [tok][d]
                ob[idx] = f2bf(acc[i][j][rr] + bia);
            }
        }
    }
}

// ---------------------------------------------------------------------------
// Fused scale-0 attention, kv-split x2. 512 thr = 8 waves (wm 0..1 x wn 0..3).
#define PS_STRIDE 136

__global__ __launch_bounds__(512) void flash0(
    const unsigned short* __restrict__ qt, const unsigned short* __restrict__ kt,
    const unsigned short* __restrict__ vt, float* __restrict__ part,
    float* __restrict__ rs0g)
{
    __shared__ unsigned short Ps[64 * PS_STRIDE];   // 17.4 KB
    __shared__ unsigned short Bs[256 * 64];         // 32 KB linear swizzled

    int L = blockIdx.x;
    int xcd = L & 7, slot = L >> 3;
    int b = xcd >> 1;
    int idx = slot + 64 * (xcd & 1);
    int h = idx >> 6;
    int q0 = (idx & 63) * 64;
    int kvbase = h * 2048;

    const unsigned short* Qb = qt + (size_t)b * TOK;
    const unsigned short* Kb = kt + (size_t)b * TOK;
    const unsigned short* Vb = vt + (size_t)b * TOK;

    int t = threadIdx.x, w = t >> 6, lane = t & 63;
    int quad = lane >> 4, lr = lane & 15;
    int wm = w >> 2, wn = w & 3;

    bf16x8 aq[4][2][2];
    #pragma unroll
    for (int k = 0; k < 4; k++)
        #pragma unroll
        for (int s = 0; s < 2; s++)
            #pragma unroll
            for (int i = 0; i < 2; i++)
                aq[k][s][i] = *(const bf16x8*)&Qb[
                    (size_t)(q0 + wm*32 + i*16 + lr) * 256 + k*64 + s*32 + quad*8];

    f32x4 acc_o[2][4];
    #pragma unroll
    for (int i = 0; i < 2; i++)
        #pragma unroll
        for (int j = 0; j < 4; j++) acc_o[i][j] = (f32x4){0.f, 0.f, 0.f, 0.f};
    float rsum[2][4] = {};

    const float SC = 1.f / 16.f;

    for (int kv0 = kvbase; kv0 < kvbase + 2048; kv0 += 128) {
        f32x4 acc_s[2][2];
        #pragma unroll
        for (int i = 0; i < 2; i++)
            #pragma unroll
            for (int j = 0; j < 2; j++) acc_s[i][j] = (f32x4){0.f, 0.f, 0.f, 0.f};

        #pragma unroll
        for (int kp = 0; kp < 2; kp++) {
            __syncthreads();
            #pragma unroll
            for (int k = 0; k < 4; k++) {
                int n = t + k * 512;
                int R = n >> 3, sl = n & 7;
                int kl = R & 127, dsub = R >> 7;
                const char* gp = (const char*)(Kb + (size_t)(kv0 + kl) * 256
                                 + kp*128 + dsub*64) + ((sl ^ (R & 7)) << 4);
                gload16(gp, (char*)Bs + n * 16);
            }
            __syncthreads();
            __builtin_amdgcn_s_setprio(1);
            #pragma unroll
            for (int t2 = 0; t2 < 2; t2++)
                #pragma unroll
                for (int s = 0; s < 2; s++) {
                    bf16x8 bfr[2];
                    #pragma unroll
                    for (int j = 0; j < 2; j++) {
                        int row = t2*128 + wn*32 + j*16 + lr;
                        int off = (row << 7) + (s << 6) + (quad << 4);
                        bfr[j] = *(const bf16x8*)((const char*)Bs
                                   + (off ^ ((row & 7) << 4)));
                    }
                    #pragma unroll
                    for (int i = 0; i < 2; i++)
                        #pragma unroll
                        for (int j = 0; j < 2; j++)
                            acc_s[i][j] = __builtin_amdgcn_mfma_f32_16x16x32_bf16(
                                aq[kp*2 + t2][s][i], bfr[j], acc_s[i][j], 0, 0, 0);
                }
            __builtin_amdgcn_s_setprio(0);
        }

        #pragma unroll
        for (int i = 0; i < 2; i++)
            #pragma unroll
            for (int j = 0; j < 2; j++)
                #pragma unroll
                for (int rr = 0; rr < 4; rr++) {
                    float e = __expf(acc_s[i][j][rr] * SC);
                    Ps[(wm*32 + i*16 + quad*4 + rr) * PS_STRIDE + wn*32 + j*16 + lr]
                        = f2bf(e);
                    rsum[i][rr] += e;
                }

        #pragma unroll
        for (int ks = 0; ks < 2; ks++) {
            __syncthreads();
            #pragma unroll
            for (int k = 0; k < 4; k++) {
                int n = t + k * 512;
                int R = n >> 3, sl = n & 7;
                const char* gp = (const char*)(Vb + (size_t)R * 4096 + kv0 + ks*64)
                               + ((sl ^ (R & 7)) << 4);
                gload16(gp, (char*)Bs + n * 16);
            }
            __syncthreads();
            __builtin_amdgcn_s_setprio(1);
            #pragma unroll
            for (int s = 0; s < 2; s++) {
                bf16x8 pa[2], vb[4];
                #pragma unroll
                for (int i = 0; i < 2; i++)
                    pa[i] = *(const bf16x8*)&Ps[
                        (wm*32 + i*16 + lr) * PS_STRIDE + ks*64 + s*32 + quad*8];
                #pragma unroll
                for (int j = 0; j < 4; j++) {
                    int row = wn*64 + j*16 + lr;
                    int off = (row << 7) + (s << 6) + (quad << 4);
                    vb[j] = *(const bf16x8*)((const char*)Bs
                              + (off ^ ((row & 7) << 4)));
                }
                #pragma unroll
                for (int i = 0; i < 2; i++)
                    #pragma unroll
                    for (int j = 0; j < 4; j++)
                        acc_o[i][j] = __builtin_amdgcn_mfma_f32_16x16x32_bf16(
                            pa[i], vb[j], acc_o[i][j], 0, 0, 0);
            }
            __builtin_amdgcn_s_setprio(0);
        }
    }

    #pragma unroll
    for (int i = 0; i < 2; i++)
        #pragma unroll
        for (int rr = 0; rr < 4; rr++) {
            float v = rsum[i][rr];
            v += __shfl_xor(v, 1); v += __shfl_xor(v, 2);
            v += __shfl_xor(v, 4); v += __shfl_xor(v, 8);
            if (lr == 0)
                atomicAdd(&rs0g[b * 4096 + q0 + wm*32 + i*16 + quad*4 + rr], v);
        }
    float* op = part + ((size_t)(h * 4 + b)) * TOK;
    #pragma unroll
    for (int i = 0; i < 2; i++)
        #pragma unroll
        for (int rr = 0; rr < 4; rr++) {
            int tokl = wm*32 + i*16 + quad*4 + rr;
            float* orow = op + (size_t)(q0 + tokl) * 256;
            #pragma unroll
            for (int j = 0; j < 4; j++)
                orow[wn*64 + j*16 + lr] = acc_o[i][j][rr];
        }
}

// ---------------------------------------------------------------------------
// Sum 2 kv-half partials, divide by rowsum, scatter padded NHWC. grid (256,4).
__global__ __launch_bounds__(256) void combine0f(
    const float* __restrict__ part, const float* __restrict__ rs,
    unsigned short* __restrict__ aotp)
{
    int b = blockIdx.y;
    int tok0 = blockIdx.x * 16;
    const float* p0 = part + (size_t)b * TOK;
    const float* p1 = part + (size_t)(4 + b) * TOK;
    int t = threadIdx.x;
    int w = t >> 6, ch = t & 63;
    int wy = w >> 1, wx = w & 1;
    #pragma unroll 4
    for (int u = 0; u < 16; u++) {
        int tok = tok0 + u;
        size_t base = (size_t)tok * 256 + ch * 4 + w;
        float v = (p0[base] + p1[base]) * (1.f / rs[b * 4096 + tok]);
        int oy = tok >> 6, ox = tok & 63;
        int yy = oy * 2 + wy, xx = ox * 2 + wx;
        aotp[((size_t)(b * 130 + yy + 1) * 130 + xx + 1) * CC + ch] = f2bf(v);
    }
}

// ---------------------------------------------------------------------------
// E = exp(sc * Q K^T) + rowsum atomics. Scale 1.
template<int NTOK, int DD>
__global__ __launch_bounds__(256) void s_gemm_exp(
    const unsigned short* __restrict__ Qb, const unsigned short* __restrict__ Kb,
    unsigned short* __restrict__ S0, float* __restrict__ rsg, float sc)
{
    __shared__ unsigned short Asb[2][8192], Bsb[2][8192];
    int bz = blockIdx.z;
    int m0 = blockIdx.y * 128, n0 = blockIdx.x * 128;
    const unsigned short* Q = Qb + (size_t)bz * TOK + (size_t)m0 * DD;
    const unsigned short* K = Kb + (size_t)bz * TOK + (size_t)n0 * DD;
    unsigned short* S = S0 + (size_t)bz * NTOK * NTOK;
    float* rs = rsg + (size_t)bz * NTOK;

    int t = threadIdx.x, w = t >> 6, lane = t & 63;
    int quad = lane >> 4, lr = lane & 15, wm = w >> 1, wn = w & 1;

    f32x4 acc[4][4];
    #pragma unroll
    for (int i = 0; i < 4; i++)
        #pragma unroll
        for (int j = 0; j < 4; j++) acc[i][j] = (f32x4){0.f, 0.f, 0.f, 0.f};

    stage64(Q, DD, Asb[0], t);
    stage64(K, DD, Bsb[0], t);
    __syncthreads();
    int cur = 0;
    for (int k0 = 0; k0 < DD; k0 += 64) {
        if (k0 + 64 < DD) {
            stage64(Q + k0 + 64, DD, Asb[cur ^ 1], t);
            stage64(K + k0 + 64, DD, Bsb[cur ^ 1], t);
        }
        mfma_iter_swz(Asb[cur], Bsb[cur], wm, wn, lr, quad, acc);
        __syncthreads();
        cur ^= 1;
    }

    #pragma unroll
    for (int i = 0; i < 4; i++) {
        int m = m0 + wm * 64 + i * 16 + quad * 4;
        float rsum[4] = {0.f, 0.f, 0.f, 0.f};
        #pragma unroll
        for (int j = 0; j < 4; j++) {
            int n = n0 + wn * 64 + j * 16 + lr;
            #pragma unroll
            for (int rr = 0; rr < 4; rr++) {
                float e = __expf(acc[i][j][rr] * sc);
                S[(size_t)(m + rr) * NTOK + n] = f2bf(e);
                rsum[rr] += e;
            }
        }
        #pragma unroll
        for (int rr = 0; rr < 4; rr++) {
            float v = rsum[rr];
            v += __shfl_xor(v, 1);
            v += __shfl_xor(v, 2);
            v += __shfl_xor(v, 4);
            v += __shfl_xor(v, 8);
            if (lr == 0) atomicAdd(&rs[m + rr], v);
        }
    }
}

// ---------------------------------------------------------------------------
// O = E V (V [d][tok]); divide by rowsum; padded NHWC scatter. Scales 1,2.
template<int NTOK, int DD, int LG, int CH0>
__global__ __launch_bounds__(256) void o_gemm(
    const unsigned short* __restrict__ Pb, const unsigned short* __restrict__ Vb,
    const float* __restrict__ rsg, unsigned short* __restrict__ aotp, int b0)
{
    __shared__ unsigned short Asb[2][8192], Bsb[2][8192];
    int bz = blockIdx.z, b = b0 + bz;
    int m0 = blockIdx.y * 128, n0 = blockIdx.x * 128;
    const unsigned short* P = Pb + (size_t)bz * NTOK * NTOK + (size_t)m0 * NTOK;
    const unsigned short* V = Vb + (size_t)bz * TOK + (size_t)n0 * NTOK;
    const float* rs = rsg + (size_t)bz * NTOK;

    int t = threadIdx.x, w = t >> 6, lane = t & 63;
    int quad = lane >> 4, lr = lane & 15, wm = w >> 1, wn = w & 1;

    f32x4 acc[4][4];
    #pragma unroll
    for (int i = 0; i < 4; i++)
        #pragma unroll
        for (int j = 0; j < 4; j++) acc[i][j] = (f32x4){0.f, 0.f, 0.f, 0.f};

    stage64(P, NTOK, Asb[0], t);
    stage64(V, NTOK, Bsb[0], t);
    __syncthreads();
    int cur = 0;
    for (int k0 = 0; k0 < NTOK; k0 += 64) {
        if (k0 + 64 < NTOK) {
            stage64(P + k0 + 64, NTOK, Asb[cur ^ 1], t);
            stage64(V + k0 + 64, NTOK, Bsb[cur ^ 1], t);
        }
        mfma_iter_swz(Asb[cur], Bsb[cur], wm, wn, lr, quad, acc);
        __syncthreads();
        cur ^= 1;
    }

    #pragma unroll
    for (int i = 0; i < 4; i++) {
        int tb0 = m0 + wm * 64 + i * 16 + quad * 4;
        #pragma unroll
        for (int rr = 0; rr < 4; rr++) {
            int tokn = tb0 + rr;
            float inv = 1.f / rs[tokn];
            int oy = tokn >> (7 - LG), ox = tokn & ((1 << (7 - LG)) - 1);
            #pragma unroll
            for (int j = 0; j < 4; j++) {
                int d = n0 + wn * 64 + j * 16 + lr;
                int ch = d >> (2 * LG);
                int r2 = d & ((1 << (2 * LG)) - 1);
                int wy = r2 >> LG, wx = r2 & ((1 << LG) - 1);
                int yy = (oy << LG) + wy, xx = (ox << LG) + wx;
                aotp[((size_t)(b * 130 + yy + 1) * 130 + xx + 1) * CC + CH0 + ch] =
                    f2bf(acc[i][j][rr] * inv);
            }
        }
    }
}

// ---------------------------------------------------------------------------
// Scale-2 score GEMM, 8-way K-split, fp32 partials. grid (2,2,32).
__global__ __launch_bounds__(256) void s2_partial(
    const unsigned short* __restrict__ Qb, const unsigned short* __restrict__ Kb,
    float* __restrict__ S2p)
{
    __shared__ unsigned short Asb[2][8192], Bsb[2][8192];
    int z = blockIdx.z, b = z >> 3, sp = z & 7;
    int m0 = blockIdx.y * 128, n0 = blockIdx.x * 128;
    const unsigned short* Q = Qb + (size_t)b * TOK + (size_t)m0 * 4096 + sp * 512;
    const unsigned short* K = Kb + (size_t)b * TOK + (size_t)n0 * 4096 + sp * 512;
    float* So = S2p + ((size_t)(sp * 4 + b)) * 65536;

    int t = threadIdx.x, w = t >> 6, lane = t & 63;
    int quad = lane >> 4, lr = lane & 15, wm = w >> 1, wn = w & 1;

    f32x4 acc[4][4];
    #pragma unroll
    for (int i = 0; i < 4; i++)
        #pragma unroll
        for (int j = 0; j < 4; j++) acc[i][j] = (f32x4){0.f, 0.f, 0.f, 0.f};

    stage64(Q, 4096, Asb[0], t);
    stage64(K, 4096, Bsb[0], t);
    __syncthreads();
    int cur = 0;
    for (int k0 = 0; k0 < 512; k0 += 64) {
        if (k0 + 64 < 512) {
            stage64(Q + k0 + 64, 4096, Asb[cur ^ 1], t);
            stage64(K + k0 + 64, 4096, Bsb[cur ^ 1], t);
        }
        mfma_iter_swz(Asb[cur], Bsb[cur], wm, wn, lr, quad, acc);
        __syncthreads();
        cur ^= 1;
    }

    #pragma unroll
    for (int i = 0; i < 4; i++) {
        int m = m0 + wm * 64 + i * 16 + quad * 4;
        #pragma unroll
        for (int j = 0; j < 4; j++) {
            int n = n0 + wn * 64 + j * 16 + lr;
            #pragma unroll
            for (int rr = 0; rr < 4; rr++)
                So[(size_t)(m + rr) * 256 + n] = acc[i][j][rr];
        }
    }
}

// Sum 8 partials, exp, write bf16 S + rowsum. grid (256 rows, 4 b).
__global__ __launch_bounds__(256) void s2_finish(
    const float* __restrict__ S2p, unsigned short* __restrict__ Sbf,
    float* __restrict__ rs2, float sc)
{
    int row = blockIdx.x, b = blockIdx.y, t = threadIdx.x;
    float v = 0.f;
    #pragma unroll
    for (int sp = 0; sp < 8; sp++)
        v += S2p[((size_t)(sp * 4 + b)) * 65536 + row * 256 + t];
    float e = __expf(v * sc);
    Sbf[((size_t)b * 65536) + row * 256 + t] = f2bf(e);
    __shared__ float red[256];
    red[t] = e; __syncthreads();
    for (int s = 128; s > 0; s >>= 1) {
        if (t < s) red[t] += red[t + s];
        __syncthreads();
    }
    if (t == 0) rs2[b * 256 + row] = red[0];
}

// ---------------------------------------------------------------------------
// conv3x3 on padded NHWC (no boundary branches) + fused BN-stats partials.
// grid: (128 y-rows, 2 o-tiles, 4 b). K = 9 taps x 4 c-chunks = 36 steps.
__global__ __launch_bounds__(256) void conv_gemm(
    const unsigned short* __restrict__ aotp, const unsigned short* __restrict__ wpack,
    const float* __restrict__ bo, float* __restrict__ zout,
    float* __restrict__ stats)
{
    __shared__ unsigned short Asb[2][8192], Bsb[2][8192];
    int yrow = blockIdx.x;
    int o0 = blockIdx.y * 128;
    int b = blockIdx.z;
    const unsigned short* aob = aotp + (size_t)b * 130 * 130 * 256;
    const unsigned short* wsrc = wpack + (size_t)o0 * 2304;

    int t = threadIdx.x, w = t >> 6, lane = t & 63;
    int quad = lane >> 4, lr = lane & 15, wm = w >> 1, wn = w & 1;

    f32x4 acc[4][4];
    #pragma unroll
    for (int i = 0; i < 4; i++)
        #pragma unroll
        for (int j = 0; j < 4; j++) acc[i][j] = (f32x4){0.f, 0.f, 0.f, 0.f};

    // K-step kk: tap = kk>>2, cb = (kk&3)*64
    stage64(wsrc, 2304, Asb[0], t);
    {
        int ys = yrow - 1;          // tap 0: dy=-1, dx=-1
        stage64(aob + ((size_t)(ys + 1) * 130 + 0) * 256, 256, Bsb[0], t);
    }
    __syncthreads();
    int cur = 0;
    for (int kk = 0; kk < 36; kk++) {
        if (kk + 1 < 36) {
            int kn = kk + 1;
            int tap = kn >> 2, cb = (kn & 3) * 64;
            int dy = tap / 3 - 1, dx = tap % 3 - 1;
            int ys = yrow + dy;
            stage64(wsrc + tap * 256 + cb, 2304, Asb[cur ^ 1], t);
            stage64(aob + ((size_t)(ys + 1) * 130 + (dx + 1)) * 256 + cb, 256,
                    Bsb[cur ^ 1], t);
        }
        mfma_iter_swz(Asb[cur], Bsb[cur], wm, wn, lr, quad, acc);
        __syncthreads();
        cur ^= 1;
    }

    #pragma unroll
    for (int i = 0; i < 4; i++) {
        #pragma unroll
        for (int rr = 0; rr < 4; rr++) {
            int o = o0 + wm * 64 + i * 16 + quad * 4 + rr;
            float bia = bo[o];
            float s1 = 0.f, s2v = 0.f;
            #pragma unroll
            for (int j = 0; j < 4; j++) {
                int x = wn * 64 + j * 16 + lr;
                float v = acc[i][j][rr] + bia;
                zout[((size_t)(b * CC + o)) * HWP + yrow * WW_ + x] = v;
                s1 += v; s2v = fmaf(v, v, s2v);
            }
            s1 += __shfl_xor(s1, 1); s2v += __shfl_xor(s2v, 1);
            s1 += __shfl_xor(s1, 2); s2v += __shfl_xor(s2v, 2);
            s1 += __shfl_xor(s1, 4); s2v += __shfl_xor(s2v, 4);
            s1 += __shfl_xor(s1, 8); s2v += __shfl_xor(s2v, 8);
            if (lr == 0) {
                atomicAdd(&stats[o], s1);
                atomicAdd(&stats[CC + o], s2v);
            }
        }
    }
}

// ---------------------------------------------------------------------------
// scale-3 S via MFMA: 64x64, K=16384 (16-way split x 1024), atomic fp32 acc.
// grid (64): b = z>>4, kc = z&15. 4 waves, 32x32 quadrants.
__global__ __launch_bounds__(256) void s3_mfma(
    const unsigned short* __restrict__ Qb, const unsigned short* __restrict__ Kb,
    float* __restrict__ S, float sc)
{
    __shared__ unsigned short Asb[2][4096], Bsb[2][4096];
    int z = blockIdx.x, b = z >> 4, kc = z & 15;
    const unsigned short* Q = Qb + (size_t)b * TOK + kc * 1024;
    const unsigned short* K = Kb + (size_t)b * TOK + kc * 1024;
    float* Sb = S + (size_t)b * 4096;

    int t = threadIdx.x, w = t >> 6, lane = t & 63;
    int quad = lane >> 4, lr = lane & 15, wm = w >> 1, wn = w & 1;

    f32x4 acc[2][2];
    #pragma unroll
    for (int i = 0; i < 2; i++)
        #pragma unroll
        for (int j = 0; j < 2; j++) acc[i][j] = (f32x4){0.f, 0.f, 0.f, 0.f};

    stage32(Q, 16384, Asb[0], t);
    stage32(K, 16384, Bsb[0], t);
    __syncthreads();
    int cur = 0;
    for (int k0 = 0; k0 < 1024; k0 += 64) {
        if (k0 + 64 < 1024) {
            stage32(Q + k0 + 64, 16384, Asb[cur ^ 1], t);
            stage32(K + k0 + 64, 16384, Bsb[cur ^ 1], t);
        }
        #pragma unroll
        for (int s = 0; s < 2; s++) {
            bf16x8 af[2], bfr[2];
            #pragma unroll
            for (int i = 0; i < 2; i++) {
                int row = wm*32 + i*16 + lr;
                int off = (row << 7) + (s << 6) + (quad << 4);
                af[i] = *(const bf16x8*)((const char*)Asb[cur]
                          + (off ^ ((row & 7) << 4)));
            }
            #pragma unroll
            for (int j = 0; j < 2; j++) {
                int row = wn*32 + j*16 + lr;
                int off = (row << 7) + (s << 6) + (quad << 4);
                bfr[j] = *(const bf16x8*)((const char*)Bsb[cur]
                           + (off ^ ((row & 7) << 4)));
            }
            #pragma unroll
            for (int i = 0; i < 2; i++)
                #pragma unroll
                for (int j = 0; j < 2; j++)
                    acc[i][j] = __builtin_amdgcn_mfma_f32_16x16x32_bf16(
                        af[i], bfr[j], acc[i][j], 0, 0, 0);
        }
        __syncthreads();
        cur ^= 1;
    }

    #pragma unroll
    for (int i = 0; i < 2; i++)
        #pragma unroll
        for (int j = 0; j < 2; j++)
            #pragma unroll
            for (int rr = 0; rr < 4; rr++)
                atomicAdd(&Sb[(size_t)(wm*32 + i*16 + quad*4 + rr) * 64
                              + wn*32 + j*16 + lr],
                          acc[i][j][rr] * sc);
}

// ---------------------------------------------------------------------------
// in-place row softmax (scale 3 only). grid: (n, nb)
template<typename T>
__global__ __launch_bounds__(256) void softmax_kernel(T* __restrict__ S, int n)
{
    int b = blockIdx.y;
    int row = blockIdx.x;
    T* rp = S + (size_t)b * n * n + (size_t)row * n;
    __shared__ float red[256];
    int t = threadIdx.x;

    float m = -1e30f;
    for (int j = t; j < n; j += 256) m = fmaxf(m, ld1(&rp[j]));
    red[t] = m; __syncthreads();
    for (int s = 128; s > 0; s >>= 1) { if (t < s) red[t] = fmaxf(red[t], red[t + s]); __syncthreads(); }
    m = red[0]; __syncthreads();

    float sum = 0.f;
    for (int j = t; j < n; j += 256) { float e = __expf(ld1(&rp[j]) - m); st1(&rp[j], e); sum += e; }
    red[t] = sum; __syncthreads();
    for (int s = 128; s > 0; s >>= 1) { if (t < s) red[t] += red[t + s]; __syncthreads(); }
    float inv = 1.f / red[0];
    for (int j = t; j < n; j += 256) st1(&rp[j], ld1(&rp[j]) * inv);
}

// ---------------------------------------------------------------------------
// scale-3 O = P(64x64, normalized) V([d][tok]) via MFMA, K=64 single shot.
// grid (128 d-tiles, 1, 4 b). 4 waves, each N-range 32, M=64 full.
__global__ __launch_bounds__(256) void o3_mfma(
    const float* __restrict__ P, const unsigned short* __restrict__ Vb,
    unsigned short* __restrict__ aotp)
{
    const int CH0 = 192;
    int n0 = blockIdx.x * 128;
    int b = blockIdx.z;
    const float* Pb = P + (size_t)b * 4096;
    const unsigned short* V = Vb + (size_t)b * TOK;   // [d=16384][tok=64]

    __shared__ unsigned short As[4096];   // 64x64 bf16, swizzled
    __shared__ unsigned short Bs[8192];   // 128x64 bf16, swizzled

    int t = threadIdx.x, w = t >> 6, lane = t & 63;
    int quad = lane >> 4, lr = lane & 15;
    int wn = w;

    // P fp32 -> bf16 swizzled LDS (write XOR matches read XOR)
    #pragma unroll
    for (int k = 0; k < 2; k++) {
        int u = t + k * 256;
        int row = u >> 3, slot = u & 7;
        const float* pp = &Pb[(row << 6) + (slot << 3)];
        unsigned short tmp[8];
        #pragma unroll
        for (int e = 0; e < 8; e++) tmp[e] = f2bf(pp[e]);
        int off = ((row << 7) + (slot << 4)) ^ ((row & 7) << 4);
        *(uint4*)((char*)As + off) = *(const uint4*)tmp;
    }
    stage64(V + (size_t)n0 * 64, 64, Bs, t);
    __syncthreads();

    f32x4 acc[4][2];
    #pragma unroll
    for (int i = 0; i < 4; i++)
        #pragma unroll
        for (int j = 0; j < 2; j++) acc[i][j] = (f32x4){0.f, 0.f, 0.f, 0.f};

    #pragma unroll
    for (int s = 0; s < 2; s++) {
        bf16x8 af[4], bfr[2];
        #pragma unroll
        for (int i = 0; i < 4; i++) {
            int row = i*16 + lr;
            int off = (row << 7) + (s << 6) + (quad << 4);
            af[i] = *(const bf16x8*)((const char*)As + (off ^ ((row & 7) << 4)));
        }
        #pragma unroll
        for (int j = 0; j < 2; j++) {
            int row = wn*32 + j*16 + lr;
            int off = (row << 7) + (s << 6) + (quad << 4);
            bfr[j] = *(const bf16x8*)((const char*)Bs + (off ^ ((row & 7) << 4)));
        }
        #pragma unroll
        for (int i = 0; i < 4; i++)
            #pragma unroll
            for (int j = 0; j < 2; j++)
                acc[i][j] = __builtin_amdgcn_mfma_f32_16x16x32_bf16(
                    af[i], bfr[j], acc[i][j], 0, 0, 0);
    }

    #pragma unroll
    for (int i = 0; i < 4; i++)
        #pragma unroll
        for (int rr = 0; rr < 4; rr++) {
            int tok = i*16 + quad*4 + rr;
            int oy = tok >> 3, ox = tok & 7;
            #pragma unroll
            for (int j = 0; j < 2; j++) {
                int d = n0 + wn*32 + j*16 + lr;
                int ch = d >> 8;
                int r2 = d & 255;
                int wy = r2 >> 4, wx = r2 & 15;
                int yy = oy * 16 + wy, xx = ox * 16 + wx;
                aotp[((size_t)(b * 130 + yy + 1) * 130 + xx + 1) * CC + CH0 + ch]
                    = f2bf(acc[i][j][rr]);
            }
        }
}

// ---------------------------------------------------------------------------
// BN apply with fused finalize (reads raw sum/sumsq). grid (16384).
__global__ __launch_bounds__(256) void bn_apply_kernel(
    float* __restrict__ z, const float* __restrict__ stats,
    const float* __restrict__ gamma, const float* __restrict__ beta)
{
    size_t i4 = (size_t)blockIdx.x * 256 + threadIdx.x;
    size_t idx = i4 * 4;
    int c = (int)((idx >> 14) & 255);
    const float inv_n = 1.f / (BN * HWP);
    float mean = stats[c] * inv_n;
    float var = stats[CC + c] * inv_n - mean * mean;
    float rstd = rsqrtf(var + 1e-5f);
    float gs = gamma[c] * rstd;
    float gb = beta[c] - mean * gs;
    float4 v = *(float4*)&z[idx];
    v.x = fmaf(v.x, gs, gb); v.y = fmaf(v.y, gs, gb);
    v.z = fmaf(v.z, gs, gb); v.w = fmaf(v.w, gs, gb);
    v.x = v.x >= 0.f ? v.x : 0.2f * v.x;
    v.y = v.y >= 0.f ? v.y : 0.2f * v.y;
    v.z = v.z >= 0.f ? v.z : 0.2f * v.z;
    v.w = v.w >= 0.f ? v.w : 0.2f * v.w;
    *(float4*)&z[idx] = v;
}

// ---------------------------------------------------------------------------
extern "C" void kernel_launch(void* const* d_in, const int* in_sizes, int n_in,
                              void* d_out, int out_size, void* d_ws, size_t ws_size,
                              hipStream_t stream)
{
    const float* x     = (const float*)d_in[0];
    const float* y     = (const float*)d_in[1];
    const float* Wq    = (const float*)d_in[2];
    const float* bq    = (const float*)d_in[3];
    const float* Wk    = (const float*)d_in[4];
    const float* bk    = (const float*)d_in[5];
    const float* Wv    = (const float*)d_in[6];
    const float* bv    = (const float*)d_in[7];
    const float* Wo    = (const float*)d_in[8];
    const float* bo    = (const float*)d_in[9];
    const float* gamma = (const float*)d_in[10];
    const float* beta  = (const float*)d_in[11];
    float* out = (float*)d_out;

    unsigned short* qt    = (unsigned short*)d_ws;
    unsigned short* kt    = qt + (size_t)16777216;
    unsigned short* vt    = kt + (size_t)16777216;
    unsigned short* aotp  = vt + (size_t)16777216;          // padded, 17,305,600 shorts
    unsigned short* Sbf   = aotp + (size_t)17305600;        // 4,194,304 shorts
    unsigned short* wpack = Sbf + (size_t)4194304;          // 589,824 shorts
    unsigned short* Wqkv  = wpack + (size_t)589824;         // 196,608 shorts
    float* stats = (float*)(Wqkv + (size_t)196608);
    float* S3    = stats + 512;
    float* rs0   = S3 + 16384;     // [4][4096]
    float* rs1   = rs0 + 16384;    // [4][1024]
    float* rs2   = rs1 + 4096;     // [4][256]

    // d_out scratch:
    unsigned short* xt = (unsigned short*)d_out;                       // 33.5 MB
    unsigned short* yt = (unsigned short*)((char*)d_out + 33554432);   // 33.5 MB
    float* part = (float*)d_out;          // flash0 partials (xt dead by then)
    float* S2p  = (float*)d_out;          // scale-2 partials (part dead by then)

    dim3 blk(256);

    // zero stats(512)+S3(16384)+rs0(16384)+rs1(4096)+rs2(1024) = 38400 floats
    zero_kernel<<<dim3(150), blk, 0, stream>>>(stats);
    // zero padded aot (halo must be 0; interior fully overwritten later)
    zero4<<<dim3(2048), blk, 0, stream>>>((uint4*)aotp, 2163200);

    nchw_to_nhwc<<<dim3(256, 4, 8), blk, 0, stream>>>(x, y, xt, yt);
    wpack_kernel<<<dim3(256), blk, 0, stream>>>(Wo, wpack);
    wqkv_pack<<<dim3(3), blk, 0, stream>>>(Wq, Wk, Wv, Wqkv);

    proj_gemm<<<dim3(128, 2, 12), blk, 0, stream>>>(
        xt, yt, Wqkv, bq, bk, bv, qt, kt, vt);

    // scale 0: n=4096, D=256, window 2 — fused flash, kv-split x2
    flash0<<<dim3(512), dim3(512), 0, stream>>>(qt, kt, vt, part, rs0);
    combine0f<<<dim3(256, 4), blk, 0, stream>>>(part, rs0, aotp);

    // scale 1: n=1024, D=1024, window 4
    s_gemm_exp<1024, 1024><<<dim3(8, 8, 4), blk, 0, stream>>>(
        qt + (size_t)4 * TOK, kt + (size_t)4 * TOK, Sbf, rs1, 1.f / 32.f);
    o_gemm<1024, 1024, 2, 64><<<dim3(8, 8, 4), blk, 0, stream>>>(
        Sbf, vt + (size_t)4 * TOK, rs1, aotp, 0);

    // scale 2: n=256, D=4096, window 8 — 8-way K-split into d_out scratch
    s2_partial<<<dim3(2, 2, 32), blk, 0, stream>>>(
        qt + (size_t)8 * TOK, kt + (size_t)8 * TOK, S2p);
    s2_finish<<<dim3(256, 4), blk, 0, stream>>>(S2p, Sbf, rs2, 1.f / 64.f);
    o_gemm<256, 4096, 3, 128><<<dim3(32, 2, 4), blk, 0, stream>>>(
        Sbf, vt + (size_t)8 * TOK, rs2, aotp, 0);

    // scale 3: n=64, D=16384, window 16 — MFMA path
    s3_mfma<<<dim3(64), blk, 0, stream>>>(
        qt + (size_t)12 * TOK, kt + (size_t)12 * TOK, S3, 1.f / 128.f);
    softmax_kernel<float><<<dim3(64, 4), blk, 0, stream>>>(S3, 64);
    o3_mfma<<<dim3(128, 1, 4), blk, 0, stream>>>(S3, vt + (size_t)12 * TOK, aotp);

    // conv3x3 (padded, new engine) + fused BN stats, then apply
    conv_gemm<<<dim3(128, 2, 4), blk, 0, stream>>>(aotp, wpack, bo, out, stats);
    bn_apply_kernel<<<dim3(16384), blk, 0, stream>>>(out, stats, gamma, beta);
}